// Round 1
// baseline (737.357 us; speedup 1.0000x reference)
//
#include <hip/hip_runtime.h>

#define ATT_SLOPE 0.2f
#define ACT_SLOPE 0.01f

__device__ __forceinline__ float lrelu(float v, float s) {
    // for 0<s<1: max(v, s*v) == leaky_relu(v, s)
    return fmaxf(v, v * s);
}

// ---------------- CSR build (edges grouped by dst, self loops appended) ----------------

__global__ __launch_bounds__(256) void k_count(const int* __restrict__ ei, int E, int N,
                                               int* __restrict__ deg) {
    int i = blockIdx.x * 256 + threadIdx.x;
    int total = E + N;
    if (i >= total) return;
    int dst = (i < E) ? ei[E + i] : (i - E);
    atomicAdd(&deg[dst], 1);
}

__global__ __launch_bounds__(256) void k_scan_block(const int* __restrict__ deg, int n,
                                                    int* __restrict__ rp1, int* __restrict__ bsum) {
    __shared__ int s[256];
    int tid = threadIdx.x;
    int i = blockIdx.x * 256 + tid;
    s[tid] = (i < n) ? deg[i] : 0;
    __syncthreads();
    for (int off = 1; off < 256; off <<= 1) {
        int t = (tid >= off) ? s[tid - off] : 0;
        __syncthreads();
        s[tid] += t;
        __syncthreads();
    }
    if (i < n) rp1[i] = s[tid];                 // inclusive scan within block
    if (tid == 255) bsum[blockIdx.x] = s[255];
}

__global__ __launch_bounds__(256) void k_scan_bsum(const int* __restrict__ bsum, int nb,
                                                   int* __restrict__ boff) {
    __shared__ int s[256];
    int tid = threadIdx.x;
    s[tid] = (tid < nb) ? bsum[tid] : 0;
    __syncthreads();
    for (int off = 1; off < 256; off <<= 1) {
        int t = (tid >= off) ? s[tid - off] : 0;
        __syncthreads();
        s[tid] += t;
        __syncthreads();
    }
    if (tid < nb) boff[tid] = (tid > 0) ? s[tid - 1] : 0;   // exclusive
}

__global__ __launch_bounds__(256) void k_scan_add(int* __restrict__ rowptr,
                                                  const int* __restrict__ boff, int n) {
    int i = blockIdx.x * 256 + threadIdx.x;
    if (i < n) rowptr[i + 1] += boff[blockIdx.x];
    if (i == 0) rowptr[0] = 0;
}

__global__ __launch_bounds__(256) void k_scatter(const int* __restrict__ ei, int E, int N,
                                                 const int* __restrict__ rowptr,
                                                 int* __restrict__ cursor, int* __restrict__ adj) {
    int i = blockIdx.x * 256 + threadIdx.x;
    int total = E + N;
    if (i >= total) return;
    int src, dst;
    if (i < E) { src = ei[i]; dst = ei[E + i]; } else { src = i - E; dst = i - E; }
    int pos = atomicAdd(&cursor[dst], 1);
    adj[rowptr[dst] + pos] = src;
}

// ---------------- Dual linear: out[n, COUT] = [A @ W0^T + b0 | A @ W1^T + b1] ----------------
// A: [n, 128]; W0,W1: [COUT/2, 128]. BM=64 rows/block, 256 threads, micro-tile 8 x (COUT/32).

template <int COUT>
__global__ __launch_bounds__(256) void gemm_dual(const float* __restrict__ A, int n_rows,
                                                 const float* __restrict__ W0,
                                                 const float* __restrict__ W1,
                                                 const float* __restrict__ B0,
                                                 const float* __restrict__ B1,
                                                 float* __restrict__ out) {
    constexpr int K = 128;
    constexpr int BM = 64;
    constexpr int BK = 32;
    constexpr int TM = 8;
    constexpr int TN = COUT / 32;   // 8 (COUT=256) or 4 (COUT=128)
    __shared__ float As[BK][BM];
    __shared__ float Ws[BK][COUT];
    const int tid = threadIdx.x;
    const int tr = tid >> 5;        // 0..7  (row group)
    const int tc = tid & 31;        // 0..31 (col group)
    const int m0 = blockIdx.x * BM;
    float acc[TM][TN] = {};

    for (int kk = 0; kk < K; kk += BK) {
        // stage A tile (64 x 32)
        #pragma unroll
        for (int it = 0; it < 2; ++it) {
            int r = (tid >> 3) + it * 32;      // 0..63
            int c4 = (tid & 7) * 4;            // 0..28
            int gr = m0 + r;
            float4 v = make_float4(0.f, 0.f, 0.f, 0.f);
            if (gr < n_rows) v = *(const float4*)&A[(size_t)gr * K + kk + c4];
            As[c4 + 0][r] = v.x; As[c4 + 1][r] = v.y;
            As[c4 + 2][r] = v.z; As[c4 + 3][r] = v.w;
        }
        // stage W tile (COUT x 32), transposed into Ws[k][c]
        #pragma unroll
        for (int it = 0; it < COUT / 32; ++it) {
            int c = (tid >> 3) + it * 32;      // 0..COUT-1
            int k4 = (tid & 7) * 4;
            const float* Wp = (c < COUT / 2) ? &W0[(size_t)c * K] : &W1[(size_t)(c - COUT / 2) * K];
            float4 v = *(const float4*)&Wp[kk + k4];
            Ws[k4 + 0][c] = v.x; Ws[k4 + 1][c] = v.y;
            Ws[k4 + 2][c] = v.z; Ws[k4 + 3][c] = v.w;
        }
        __syncthreads();
        #pragma unroll
        for (int k = 0; k < BK; ++k) {
            float a[TM], w[TN];
            #pragma unroll
            for (int i = 0; i < TM; ++i) a[i] = As[k][tr * TM + i];
            #pragma unroll
            for (int j = 0; j < TN; ++j) w[j] = Ws[k][tc * TN + j];
            #pragma unroll
            for (int i = 0; i < TM; ++i)
                #pragma unroll
                for (int j = 0; j < TN; ++j) acc[i][j] += a[i] * w[j];
        }
        __syncthreads();
    }
    // epilogue: + bias, store
    #pragma unroll
    for (int i = 0; i < TM; ++i) {
        int gr = m0 + tr * TM + i;
        if (gr >= n_rows) break;
        #pragma unroll
        for (int j = 0; j < TN; ++j) {
            int c = tc * TN + j;
            float b = (c < COUT / 2) ? B0[c] : B1[c - COUT / 2];
            out[(size_t)gr * COUT + c] = acc[i][j] + b;
        }
    }
}

// ---------------- GATv2 edge phase, conv1 (heads=2, ch=64) ----------------
// buf: [N,256] = xl(128) | xr(128). One wave per dst node, CSR over incoming edges.
// Pass 1: denom = sum exp(e). Pass 2: recompute e, acc += exp(e)/denom * xl[src].
// Output h1[N,128] = lrelu(acc + bias, 0.01)  (outer activation fused).

__global__ __launch_bounds__(256) void edge_conv1(const float* __restrict__ buf,
                                                  const int* __restrict__ rowptr,
                                                  const int* __restrict__ adj,
                                                  const float* __restrict__ att,   // [128]
                                                  const float* __restrict__ bias,  // [128]
                                                  float* __restrict__ h1, int n) {
    int wid = threadIdx.x >> 6, lane = threadIdx.x & 63;
    int node = blockIdx.x * 4 + wid;
    if (node >= n) return;
    const float a0 = att[lane], a1 = att[64 + lane];
    const float xr0 = buf[(size_t)node * 256 + 128 + lane];
    const float xr1 = buf[(size_t)node * 256 + 192 + lane];
    const int s = rowptr[node], e = rowptr[node + 1];

    float denom0 = 0.f, denom1 = 0.f;
    for (int j = s; j < e; ++j) {
        int src = adj[j];
        const float* xl = &buf[(size_t)src * 256];
        float r0 = lrelu(xl[lane] + xr0, ATT_SLOPE) * a0;
        float r1 = lrelu(xl[64 + lane] + xr1, ATT_SLOPE) * a1;
        #pragma unroll
        for (int off = 32; off; off >>= 1) { r0 += __shfl_xor(r0, off); r1 += __shfl_xor(r1, off); }
        denom0 += __expf(r0);
        denom1 += __expf(r1);
    }
    const float inv0 = 1.f / denom0, inv1 = 1.f / denom1;
    float acc0 = 0.f, acc1 = 0.f;
    for (int j = s; j < e; ++j) {
        int src = adj[j];
        const float* xl = &buf[(size_t)src * 256];
        float x0 = xl[lane], x1 = xl[64 + lane];
        float r0 = lrelu(x0 + xr0, ATT_SLOPE) * a0;
        float r1 = lrelu(x1 + xr1, ATT_SLOPE) * a1;
        #pragma unroll
        for (int off = 32; off; off >>= 1) { r0 += __shfl_xor(r0, off); r1 += __shfl_xor(r1, off); }
        acc0 += __expf(r0) * inv0 * x0;
        acc1 += __expf(r1) * inv1 * x1;
    }
    h1[(size_t)node * 128 + lane]      = lrelu(acc0 + bias[lane], ACT_SLOPE);
    h1[(size_t)node * 128 + 64 + lane] = lrelu(acc1 + bias[64 + lane], ACT_SLOPE);
}

// ---------------- GATv2 edge phase, conv2 (heads=1, ch=64) ----------------
// buf: [N,128] = xl(64) | xr(64). Output h2[N,64] = lrelu(acc + bias, 0.01).

__global__ __launch_bounds__(256) void edge_conv2(const float* __restrict__ buf,
                                                  const int* __restrict__ rowptr,
                                                  const int* __restrict__ adj,
                                                  const float* __restrict__ att,   // [64]
                                                  const float* __restrict__ bias,  // [64]
                                                  float* __restrict__ h2, int n) {
    int wid = threadIdx.x >> 6, lane = threadIdx.x & 63;
    int node = blockIdx.x * 4 + wid;
    if (node >= n) return;
    const float a = att[lane];
    const float xr = buf[(size_t)node * 128 + 64 + lane];
    const int s = rowptr[node], e = rowptr[node + 1];

    float denom = 0.f;
    for (int j = s; j < e; ++j) {
        int src = adj[j];
        float r = lrelu(buf[(size_t)src * 128 + lane] + xr, ATT_SLOPE) * a;
        #pragma unroll
        for (int off = 32; off; off >>= 1) r += __shfl_xor(r, off);
        denom += __expf(r);
    }
    const float inv = 1.f / denom;
    float acc = 0.f;
    for (int j = s; j < e; ++j) {
        int src = adj[j];
        float x0 = buf[(size_t)src * 128 + lane];
        float r = lrelu(x0 + xr, ATT_SLOPE) * a;
        #pragma unroll
        for (int off = 32; off; off >>= 1) r += __shfl_xor(r, off);
        acc += __expf(r) * inv * x0;
    }
    h2[(size_t)node * 64 + lane] = lrelu(acc + bias[lane], ACT_SLOPE);
}

// ---------------- global mean pool (batch sorted) + fc1 + lrelu + fc2 ----------------

__device__ __forceinline__ int lower_bound(const int* a, int n, int v) {
    int lo = 0, hi = n;
    while (lo < hi) { int mid = (lo + hi) >> 1; if (a[mid] < v) lo = mid + 1; else hi = mid; }
    return lo;
}

__global__ __launch_bounds__(256) void pool_mlp(const float* __restrict__ h2,   // [N,64]
                                                const int* __restrict__ batch,  // [N] sorted
                                                const float* __restrict__ fc1_w,
                                                const float* __restrict__ fc1_b,
                                                const float* __restrict__ fc2_w,
                                                const float* __restrict__ fc2_b,
                                                float* __restrict__ out, int n) {
    const int g = blockIdx.x;
    const int tid = threadIdx.x;
    const int c = tid & 63, q = tid >> 6;  // 4 waves, each sums a strided slice
    __shared__ float partial[4][64];
    __shared__ float pooled[64];
    __shared__ float hmid[64];

    int lo = lower_bound(batch, n, g);
    int hi = lower_bound(batch, n, g + 1);

    float sum = 0.f;
    for (int i = lo + q; i < hi; i += 4) sum += h2[(size_t)i * 64 + c];
    partial[q][c] = sum;
    __syncthreads();
    if (q == 0) {
        float s = partial[0][c] + partial[1][c] + partial[2][c] + partial[3][c];
        int cnt = hi - lo;
        pooled[c] = s / (float)max(cnt, 1);
    }
    __syncthreads();
    if (tid < 64) {
        float acc = fc1_b[tid];
        const float* w = &fc1_w[(size_t)tid * 64];
        #pragma unroll
        for (int k = 0; k < 64; ++k) acc += pooled[k] * w[k];
        hmid[tid] = lrelu(acc, ACT_SLOPE);
    }
    __syncthreads();
    for (int o = tid; o < 768; o += 256) {
        float acc = fc2_b[o];
        const float* w = &fc2_w[(size_t)o * 64];
        #pragma unroll
        for (int k = 0; k < 64; ++k) acc += hmid[k] * w[k];
        out[(size_t)g * 768 + o] = acc;
    }
}

// ---------------- launch ----------------

extern "C" void kernel_launch(void* const* d_in, const int* in_sizes, int n_in,
                              void* d_out, int out_size, void* d_ws, size_t ws_size,
                              hipStream_t stream) {
    const float* x     = (const float*)d_in[0];
    const int*   ei    = (const int*)d_in[1];
    const int*   batch = (const int*)d_in[2];
    const float* w1_l  = (const float*)d_in[3];
    const float* b1_l  = (const float*)d_in[4];
    const float* w1_r  = (const float*)d_in[5];
    const float* b1_r  = (const float*)d_in[6];
    const float* att1  = (const float*)d_in[7];
    const float* bias1 = (const float*)d_in[8];
    const float* w2_l  = (const float*)d_in[9];
    const float* b2_l  = (const float*)d_in[10];
    const float* w2_r  = (const float*)d_in[11];
    const float* b2_r  = (const float*)d_in[12];
    const float* att2  = (const float*)d_in[13];
    const float* bias2 = (const float*)d_in[14];
    const float* fc1_w = (const float*)d_in[15];
    const float* fc1_b = (const float*)d_in[16];
    const float* fc2_w = (const float*)d_in[17];
    const float* fc2_b = (const float*)d_in[18];
    float* out = (float*)d_out;

    const int N = in_sizes[2];          // batch length
    const int E = in_sizes[1] / 2;      // edge_index is [2, E]
    const int T = E + N;                // edges + self loops
    const int G = out_size / 768;

    // workspace carve-up (256B-aligned bump allocator)
    char* ws = (char*)d_ws;
    size_t off = 0;
    auto alloc = [&](size_t bytes) -> void* {
        void* p = ws + off;
        off = (off + bytes + 255) & ~(size_t)255;
        return p;
    };
    int*   deg    = (int*)alloc((size_t)N * 4);
    int*   rowptr = (int*)alloc((size_t)(N + 1) * 4);
    int*   cursor = (int*)alloc((size_t)N * 4);
    int*   bsum   = (int*)alloc(1024);
    int*   boff   = (int*)alloc(1024);
    int*   adj    = (int*)alloc((size_t)T * 4);
    float* h1     = (float*)alloc((size_t)N * 128 * 4);
    float* buf1   = (float*)alloc((size_t)N * 256 * 4);
    // lifetime aliasing: buf1 is dead after edge_conv1; reuse its space
    float* buf2 = buf1;                       // [N,128]
    float* h2   = buf1 + (size_t)N * 128;     // [N,64]

    const int nbN  = (N + 255) / 256;   // 196 (<= 256, required by k_scan_bsum)
    const int nbT  = (T + 255) / 256;
    const int gemG = (N + 63) / 64;
    const int edgG = (N + 3) / 4;

    // ---- CSR build ----
    hipMemsetAsync(deg, 0, (size_t)N * 4, stream);
    k_count<<<nbT, 256, 0, stream>>>(ei, E, N, deg);
    k_scan_block<<<nbN, 256, 0, stream>>>(deg, N, rowptr + 1, bsum);
    k_scan_bsum<<<1, 256, 0, stream>>>(bsum, nbN, boff);
    k_scan_add<<<nbN, 256, 0, stream>>>(rowptr, boff, N);
    hipMemsetAsync(cursor, 0, (size_t)N * 4, stream);
    k_scatter<<<nbT, 256, 0, stream>>>(ei, E, N, rowptr, cursor, adj);

    // ---- conv1 ----
    gemm_dual<256><<<gemG, 256, 0, stream>>>(x, N, w1_l, w1_r, b1_l, b1_r, buf1);
    edge_conv1<<<edgG, 256, 0, stream>>>(buf1, rowptr, adj, att1, bias1, h1, N);

    // ---- conv2 ----
    gemm_dual<128><<<gemG, 256, 0, stream>>>(h1, N, w2_l, w2_r, b2_l, b2_r, buf2);
    edge_conv2<<<edgG, 256, 0, stream>>>(buf2, rowptr, adj, att2, bias2, h2, N);

    // ---- pool + MLP head ----
    pool_mlp<<<G, 256, 0, stream>>>(h2, batch, fc1_w, fc1_b, fc2_w, fc2_b, out, N);
}

// Round 2
// 622.419 us; speedup vs baseline: 1.1847x; 1.1847x over previous
//
#include <hip/hip_runtime.h>

#define ATT_SLOPE 0.2f
#define ACT_SLOPE 0.01f

__device__ __forceinline__ float lrelu(float v, float s) {
    // for 0<s<1: max(v, s*v) == leaky_relu(v, s)
    return fmaxf(v, v * s);
}

// ---------------- CSR build (edges grouped by dst, self loops appended) ----------------

__global__ __launch_bounds__(256) void k_count(const int* __restrict__ ei, int E, int N,
                                               int* __restrict__ deg) {
    int i = blockIdx.x * 256 + threadIdx.x;
    int total = E + N;
    if (i >= total) return;
    int dst = (i < E) ? ei[E + i] : (i - E);
    atomicAdd(&deg[dst], 1);
}

__global__ __launch_bounds__(256) void k_scan_block(const int* __restrict__ deg, int n,
                                                    int* __restrict__ rp1, int* __restrict__ bsum) {
    __shared__ int s[256];
    int tid = threadIdx.x;
    int i = blockIdx.x * 256 + tid;
    s[tid] = (i < n) ? deg[i] : 0;
    __syncthreads();
    for (int off = 1; off < 256; off <<= 1) {
        int t = (tid >= off) ? s[tid - off] : 0;
        __syncthreads();
        s[tid] += t;
        __syncthreads();
    }
    if (i < n) rp1[i] = s[tid];                 // inclusive scan within block
    if (tid == 255) bsum[blockIdx.x] = s[255];
}

__global__ __launch_bounds__(256) void k_scan_bsum(const int* __restrict__ bsum, int nb,
                                                   int* __restrict__ boff) {
    __shared__ int s[256];
    int tid = threadIdx.x;
    s[tid] = (tid < nb) ? bsum[tid] : 0;
    __syncthreads();
    for (int off = 1; off < 256; off <<= 1) {
        int t = (tid >= off) ? s[tid - off] : 0;
        __syncthreads();
        s[tid] += t;
        __syncthreads();
    }
    if (tid < nb) boff[tid] = (tid > 0) ? s[tid - 1] : 0;   // exclusive
}

__global__ __launch_bounds__(256) void k_scan_add(int* __restrict__ rowptr,
                                                  const int* __restrict__ boff, int n) {
    int i = blockIdx.x * 256 + threadIdx.x;
    if (i < n) rowptr[i + 1] += boff[blockIdx.x];
    if (i == 0) rowptr[0] = 0;
}

__global__ __launch_bounds__(256) void k_scatter(const int* __restrict__ ei, int E, int N,
                                                 const int* __restrict__ rowptr,
                                                 int* __restrict__ cursor,
                                                 int* __restrict__ adj, int* __restrict__ adjd) {
    int i = blockIdx.x * 256 + threadIdx.x;
    int total = E + N;
    if (i >= total) return;
    int src, dst;
    if (i < E) { src = ei[i]; dst = ei[E + i]; } else { src = i - E; dst = i - E; }
    int pos = atomicAdd(&cursor[dst], 1);
    int p = rowptr[dst] + pos;
    adj[p] = src;
    adjd[p] = dst;
}

// ---------------- Dual linear: out[n, COUT] = [A @ W0^T + b0 | A @ W1^T + b1] ----------------

template <int COUT>
__global__ __launch_bounds__(256) void gemm_dual(const float* __restrict__ A, int n_rows,
                                                 const float* __restrict__ W0,
                                                 const float* __restrict__ W1,
                                                 const float* __restrict__ B0,
                                                 const float* __restrict__ B1,
                                                 float* __restrict__ out) {
    constexpr int K = 128;
    constexpr int BM = 64;
    constexpr int BK = 32;
    constexpr int TM = 8;
    constexpr int TN = COUT / 32;   // 8 (COUT=256) or 4 (COUT=128)
    __shared__ float As[BK][BM];
    __shared__ float Ws[BK][COUT];
    const int tid = threadIdx.x;
    const int tr = tid >> 5;        // 0..7  (row group)
    const int tc = tid & 31;        // 0..31 (col group)
    const int m0 = blockIdx.x * BM;
    float acc[TM][TN] = {};

    for (int kk = 0; kk < K; kk += BK) {
        #pragma unroll
        for (int it = 0; it < 2; ++it) {
            int r = (tid >> 3) + it * 32;      // 0..63
            int c4 = (tid & 7) * 4;            // 0..28
            int gr = m0 + r;
            float4 v = make_float4(0.f, 0.f, 0.f, 0.f);
            if (gr < n_rows) v = *(const float4*)&A[(size_t)gr * K + kk + c4];
            As[c4 + 0][r] = v.x; As[c4 + 1][r] = v.y;
            As[c4 + 2][r] = v.z; As[c4 + 3][r] = v.w;
        }
        #pragma unroll
        for (int it = 0; it < COUT / 32; ++it) {
            int c = (tid >> 3) + it * 32;      // 0..COUT-1
            int k4 = (tid & 7) * 4;
            const float* Wp = (c < COUT / 2) ? &W0[(size_t)c * K] : &W1[(size_t)(c - COUT / 2) * K];
            float4 v = *(const float4*)&Wp[kk + k4];
            Ws[k4 + 0][c] = v.x; Ws[k4 + 1][c] = v.y;
            Ws[k4 + 2][c] = v.z; Ws[k4 + 3][c] = v.w;
        }
        __syncthreads();
        #pragma unroll
        for (int k = 0; k < BK; ++k) {
            float a[TM], w[TN];
            #pragma unroll
            for (int i = 0; i < TM; ++i) a[i] = As[k][tr * TM + i];
            #pragma unroll
            for (int j = 0; j < TN; ++j) w[j] = Ws[k][tc * TN + j];
            #pragma unroll
            for (int i = 0; i < TM; ++i)
                #pragma unroll
                for (int j = 0; j < TN; ++j) acc[i][j] += a[i] * w[j];
        }
        __syncthreads();
    }
    #pragma unroll
    for (int i = 0; i < TM; ++i) {
        int gr = m0 + tr * TM + i;
        if (gr >= n_rows) break;
        #pragma unroll
        for (int j = 0; j < TN; ++j) {
            int c = tc * TN + j;
            float b = (c < COUT / 2) ? B0[c] : B1[c - COUT / 2];
            out[(size_t)gr * COUT + c] = acc[i][j] + b;
        }
    }
}

// ---------------- conv1 edge phase: logits (edge-parallel) + aggregate (node-parallel) --------
// buf: [N,256] = xl(128) | xr(128).  w0,w1: exp(logit) per CSR edge slot, per head.

__global__ __launch_bounds__(256) void logits1(const float* __restrict__ buf,
                                               const int* __restrict__ adj,
                                               const int* __restrict__ adjd,
                                               const float* __restrict__ att,   // [128]
                                               float* __restrict__ w0, float* __restrict__ w1,
                                               int T) {
    int t = blockIdx.x * 256 + threadIdx.x;
    if (t >= T) return;
    int src = adj[t], dst = adjd[t];
    const float4* xl = (const float4*)&buf[(size_t)src * 256];
    const float4* xr = (const float4*)&buf[(size_t)dst * 256 + 128];
    const float4* a4 = (const float4*)att;   // wave-uniform -> scalar loads
    float s0 = 0.f, s1 = 0.f;
    #pragma unroll
    for (int k = 0; k < 16; ++k) {
        float4 l = xl[k], r = xr[k], a = a4[k];
        s0 += a.x * lrelu(l.x + r.x, ATT_SLOPE) + a.y * lrelu(l.y + r.y, ATT_SLOPE)
            + a.z * lrelu(l.z + r.z, ATT_SLOPE) + a.w * lrelu(l.w + r.w, ATT_SLOPE);
    }
    #pragma unroll
    for (int k = 16; k < 32; ++k) {
        float4 l = xl[k], r = xr[k], a = a4[k];
        s1 += a.x * lrelu(l.x + r.x, ATT_SLOPE) + a.y * lrelu(l.y + r.y, ATT_SLOPE)
            + a.z * lrelu(l.z + r.z, ATT_SLOPE) + a.w * lrelu(l.w + r.w, ATT_SLOPE);
    }
    w0[t] = __expf(s0);
    w1[t] = __expf(s1);
}

// One wave per node. Denominator: one butterfly per node. Aggregate: float2 gather-MAC,
// lane l covers channels 2l,2l+1 (l<32 -> head0, l>=32 -> head1).
__global__ __launch_bounds__(256) void agg1(const float* __restrict__ buf,
                                            const int* __restrict__ rowptr,
                                            const int* __restrict__ adj,
                                            const float* __restrict__ w0,
                                            const float* __restrict__ w1,
                                            const float* __restrict__ bias,  // [128]
                                            float* __restrict__ h1, int n) {
    int wid = threadIdx.x >> 6, lane = threadIdx.x & 63;
    int node = blockIdx.x * 4 + wid;
    if (node >= n) return;
    const int s = rowptr[node], e = rowptr[node + 1];

    float d0 = 0.f, d1 = 0.f;
    for (int j = s + lane; j < e; j += 64) { d0 += w0[j]; d1 += w1[j]; }
    #pragma unroll
    for (int off = 32; off; off >>= 1) { d0 += __shfl_xor(d0, off); d1 += __shfl_xor(d1, off); }
    const float inv0 = 1.f / d0, inv1 = 1.f / d1;
    const bool head0 = (lane < 32);

    float2 acc = make_float2(0.f, 0.f);
    for (int j = s; j < e; ++j) {
        int src = adj[j];                                   // uniform -> scalar load
        float al = head0 ? w0[j] * inv0 : w1[j] * inv1;     // w[j] uniform -> scalar load
        float2 v = *(const float2*)&buf[(size_t)src * 256 + lane * 2];
        acc.x += al * v.x;
        acc.y += al * v.y;
    }
    float2 b = *(const float2*)&bias[lane * 2];
    float2 o;
    o.x = lrelu(acc.x + b.x, ACT_SLOPE);
    o.y = lrelu(acc.y + b.y, ACT_SLOPE);
    *(float2*)&h1[(size_t)node * 128 + lane * 2] = o;
}

// ---------------- conv2 edge phase (heads=1, ch=64): buf [N,128] = xl(64) | xr(64) ------------

__global__ __launch_bounds__(256) void logits2(const float* __restrict__ buf,
                                               const int* __restrict__ adj,
                                               const int* __restrict__ adjd,
                                               const float* __restrict__ att,   // [64]
                                               float* __restrict__ w0, int T) {
    int t = blockIdx.x * 256 + threadIdx.x;
    if (t >= T) return;
    int src = adj[t], dst = adjd[t];
    const float4* xl = (const float4*)&buf[(size_t)src * 128];
    const float4* xr = (const float4*)&buf[(size_t)dst * 128 + 64];
    const float4* a4 = (const float4*)att;
    float s0 = 0.f;
    #pragma unroll
    for (int k = 0; k < 16; ++k) {
        float4 l = xl[k], r = xr[k], a = a4[k];
        s0 += a.x * lrelu(l.x + r.x, ATT_SLOPE) + a.y * lrelu(l.y + r.y, ATT_SLOPE)
            + a.z * lrelu(l.z + r.z, ATT_SLOPE) + a.w * lrelu(l.w + r.w, ATT_SLOPE);
    }
    w0[t] = __expf(s0);
}

__global__ __launch_bounds__(256) void agg2(const float* __restrict__ buf,
                                            const int* __restrict__ rowptr,
                                            const int* __restrict__ adj,
                                            const float* __restrict__ w0,
                                            const float* __restrict__ bias,  // [64]
                                            float* __restrict__ h2, int n) {
    int wid = threadIdx.x >> 6, lane = threadIdx.x & 63;
    int node = blockIdx.x * 4 + wid;
    if (node >= n) return;
    const int s = rowptr[node], e = rowptr[node + 1];

    float d = 0.f;
    for (int j = s + lane; j < e; j += 64) d += w0[j];
    #pragma unroll
    for (int off = 32; off; off >>= 1) d += __shfl_xor(d, off);
    const float inv = 1.f / d;

    float acc = 0.f;
    for (int j = s; j < e; ++j) {
        int src = adj[j];
        float al = w0[j] * inv;
        acc += al * buf[(size_t)src * 128 + lane];
    }
    h2[(size_t)node * 64 + lane] = lrelu(acc + bias[lane], ACT_SLOPE);
}

// ---------------- global mean pool (batch sorted) + fc1 + lrelu + fc2 ----------------

__device__ __forceinline__ int lower_bound(const int* a, int n, int v) {
    int lo = 0, hi = n;
    while (lo < hi) { int mid = (lo + hi) >> 1; if (a[mid] < v) lo = mid + 1; else hi = mid; }
    return lo;
}

__global__ __launch_bounds__(256) void pool_mlp(const float* __restrict__ h2,   // [N,64]
                                                const int* __restrict__ batch,  // [N] sorted
                                                const float* __restrict__ fc1_w,
                                                const float* __restrict__ fc1_b,
                                                const float* __restrict__ fc2_w,
                                                const float* __restrict__ fc2_b,
                                                float* __restrict__ out, int n) {
    const int g = blockIdx.x;
    const int tid = threadIdx.x;
    const int c = tid & 63, q = tid >> 6;  // 4 waves, each sums a strided slice
    __shared__ float partial[4][64];
    __shared__ float pooled[64];
    __shared__ float hmid[64];

    int lo = lower_bound(batch, n, g);
    int hi = lower_bound(batch, n, g + 1);

    float sum = 0.f;
    for (int i = lo + q; i < hi; i += 4) sum += h2[(size_t)i * 64 + c];
    partial[q][c] = sum;
    __syncthreads();
    if (q == 0) {
        float s = partial[0][c] + partial[1][c] + partial[2][c] + partial[3][c];
        int cnt = hi - lo;
        pooled[c] = s / (float)max(cnt, 1);
    }
    __syncthreads();
    if (tid < 64) {
        float acc = fc1_b[tid];
        const float* w = &fc1_w[(size_t)tid * 64];
        #pragma unroll
        for (int k = 0; k < 64; ++k) acc += pooled[k] * w[k];
        hmid[tid] = lrelu(acc, ACT_SLOPE);
    }
    __syncthreads();
    for (int o = tid; o < 768; o += 256) {
        float acc = fc2_b[o];
        const float* w = &fc2_w[(size_t)o * 64];
        #pragma unroll
        for (int k = 0; k < 64; ++k) acc += hmid[k] * w[k];
        out[(size_t)g * 768 + o] = acc;
    }
}

// ---------------- launch ----------------

extern "C" void kernel_launch(void* const* d_in, const int* in_sizes, int n_in,
                              void* d_out, int out_size, void* d_ws, size_t ws_size,
                              hipStream_t stream) {
    const float* x     = (const float*)d_in[0];
    const int*   ei    = (const int*)d_in[1];
    const int*   batch = (const int*)d_in[2];
    const float* w1_l  = (const float*)d_in[3];
    const float* b1_l  = (const float*)d_in[4];
    const float* w1_r  = (const float*)d_in[5];
    const float* b1_r  = (const float*)d_in[6];
    const float* att1  = (const float*)d_in[7];
    const float* bias1 = (const float*)d_in[8];
    const float* w2_l  = (const float*)d_in[9];
    const float* b2_l  = (const float*)d_in[10];
    const float* w2_r  = (const float*)d_in[11];
    const float* b2_r  = (const float*)d_in[12];
    const float* att2  = (const float*)d_in[13];
    const float* bias2 = (const float*)d_in[14];
    const float* fc1_w = (const float*)d_in[15];
    const float* fc1_b = (const float*)d_in[16];
    const float* fc2_w = (const float*)d_in[17];
    const float* fc2_b = (const float*)d_in[18];
    float* out = (float*)d_out;

    const int N = in_sizes[2];          // batch length
    const int E = in_sizes[1] / 2;      // edge_index is [2, E]
    const int T = E + N;                // edges + self loops
    const int G = out_size / 768;

    // workspace carve-up (256B-aligned bump allocator)
    char* ws = (char*)d_ws;
    size_t off = 0;
    auto alloc = [&](size_t bytes) -> void* {
        void* p = ws + off;
        off = (off + bytes + 255) & ~(size_t)255;
        return p;
    };
    int*   deg    = (int*)alloc((size_t)N * 4);
    int*   rowptr = (int*)alloc((size_t)(N + 1) * 4);
    int*   cursor = (int*)alloc((size_t)N * 4);
    int*   bsum   = (int*)alloc(1024);
    int*   boff   = (int*)alloc(1024);
    int*   adj    = (int*)alloc((size_t)T * 4);
    int*   adjd   = (int*)alloc((size_t)T * 4);
    float* ew0    = (float*)alloc((size_t)T * 4);
    float* ew1    = (float*)alloc((size_t)T * 4);
    float* h1     = (float*)alloc((size_t)N * 128 * 4);
    float* buf1   = (float*)alloc((size_t)N * 256 * 4);
    // lifetime aliasing: buf1 is dead after agg1; reuse its space
    float* buf2 = buf1;                       // [N,128]
    float* h2   = buf1 + (size_t)N * 128;     // [N,64]

    const int nbN  = (N + 255) / 256;   // 196 (<= 256, required by k_scan_bsum)
    const int nbT  = (T + 255) / 256;
    const int gemG = (N + 63) / 64;
    const int edgG = (N + 3) / 4;

    // ---- CSR build ----
    hipMemsetAsync(deg, 0, (size_t)N * 4, stream);
    k_count<<<nbT, 256, 0, stream>>>(ei, E, N, deg);
    k_scan_block<<<nbN, 256, 0, stream>>>(deg, N, rowptr + 1, bsum);
    k_scan_bsum<<<1, 256, 0, stream>>>(bsum, nbN, boff);
    k_scan_add<<<nbN, 256, 0, stream>>>(rowptr, boff, N);
    hipMemsetAsync(cursor, 0, (size_t)N * 4, stream);
    k_scatter<<<nbT, 256, 0, stream>>>(ei, E, N, rowptr, cursor, adj, adjd);

    // ---- conv1 ----
    gemm_dual<256><<<gemG, 256, 0, stream>>>(x, N, w1_l, w1_r, b1_l, b1_r, buf1);
    logits1<<<nbT, 256, 0, stream>>>(buf1, adj, adjd, att1, ew0, ew1, T);
    agg1<<<edgG, 256, 0, stream>>>(buf1, rowptr, adj, ew0, ew1, bias1, h1, N);

    // ---- conv2 ----
    gemm_dual<128><<<gemG, 256, 0, stream>>>(h1, N, w2_l, w2_r, b2_l, b2_r, buf2);
    logits2<<<nbT, 256, 0, stream>>>(buf2, adj, adjd, att2, ew0, T);
    agg2<<<edgG, 256, 0, stream>>>(buf2, rowptr, adj, ew0, bias2, h2, N);

    // ---- pool + MLP head ----
    pool_mlp<<<G, 256, 0, stream>>>(h2, batch, fc1_w, fc1_b, fc2_w, fc2_b, out, N);
}

// Round 3
// 577.963 us; speedup vs baseline: 1.2758x; 1.0769x over previous
//
#include <hip/hip_runtime.h>

#define ATT_SLOPE 0.2f
#define ACT_SLOPE 0.01f

__device__ __forceinline__ float lrelu(float v, float s) {
    return fmaxf(v, v * s);
}

// ---------------- CSR build (edges grouped by dst, self loops appended) ----------------

__global__ __launch_bounds__(256) void k_count(const int* __restrict__ ei, int E, int N,
                                               int* __restrict__ deg) {
    int i = blockIdx.x * 256 + threadIdx.x;
    int total = E + N;
    if (i >= total) return;
    int dst = (i < E) ? ei[E + i] : (i - E);
    atomicAdd(&deg[dst], 1);
}

__global__ __launch_bounds__(256) void k_scan_block(const int* __restrict__ deg, int n,
                                                    int* __restrict__ rp1, int* __restrict__ bsum) {
    __shared__ int s[256];
    int tid = threadIdx.x;
    int i = blockIdx.x * 256 + tid;
    s[tid] = (i < n) ? deg[i] : 0;
    __syncthreads();
    for (int off = 1; off < 256; off <<= 1) {
        int t = (tid >= off) ? s[tid - off] : 0;
        __syncthreads();
        s[tid] += t;
        __syncthreads();
    }
    if (i < n) rp1[i] = s[tid];
    if (tid == 255) bsum[blockIdx.x] = s[255];
}

__global__ __launch_bounds__(256) void k_scan_bsum(const int* __restrict__ bsum, int nb,
                                                   int* __restrict__ boff) {
    __shared__ int s[256];
    int tid = threadIdx.x;
    s[tid] = (tid < nb) ? bsum[tid] : 0;
    __syncthreads();
    for (int off = 1; off < 256; off <<= 1) {
        int t = (tid >= off) ? s[tid - off] : 0;
        __syncthreads();
        s[tid] += t;
        __syncthreads();
    }
    if (tid < nb) boff[tid] = (tid > 0) ? s[tid - 1] : 0;
}

__global__ __launch_bounds__(256) void k_scan_add(int* __restrict__ rowptr,
                                                  const int* __restrict__ boff, int n) {
    int i = blockIdx.x * 256 + threadIdx.x;
    if (i < n) rowptr[i + 1] += boff[blockIdx.x];
    if (i == 0) rowptr[0] = 0;
}

__global__ __launch_bounds__(256) void k_scatter(const int* __restrict__ ei, int E, int N,
                                                 const int* __restrict__ rowptr,
                                                 int* __restrict__ cursor,
                                                 int* __restrict__ adj, int* __restrict__ adjd) {
    int i = blockIdx.x * 256 + threadIdx.x;
    int total = E + N;
    if (i >= total) return;
    int src, dst;
    if (i < E) { src = ei[i]; dst = ei[E + i]; } else { src = i - E; dst = i - E; }
    int pos = atomicAdd(&cursor[dst], 1);
    int p = rowptr[dst] + pos;
    adj[p] = src;
    adjd[p] = dst;
}

// ---------------- Dual linear: out[n, COUT] = [A @ W0^T + b0 | A @ W1^T + b1] ----------------
// Conflict-free LDS: padded tiles; thread tc owns columns {j*32+tc} (lane-stride-1 reads,
// 2-way aliasing across the wave = free); As reads are broadcast.

template <int COUT>
__global__ __launch_bounds__(256) void gemm_dual(const float* __restrict__ A, int n_rows,
                                                 const float* __restrict__ W0,
                                                 const float* __restrict__ W1,
                                                 const float* __restrict__ B0,
                                                 const float* __restrict__ B1,
                                                 float* __restrict__ out) {
    constexpr int K = 128;
    constexpr int BM = 64;
    constexpr int BK = 32;
    constexpr int TM = 8;
    constexpr int TN = COUT / 32;   // 8 (COUT=256) or 4 (COUT=128)
    __shared__ float As[BK][BM + 1];
    __shared__ float Ws[BK][COUT + 1];
    const int tid = threadIdx.x;
    const int tr = tid >> 5;        // 0..7  (row group)
    const int tc = tid & 31;        // 0..31 (column within each 32-wide group)
    const int m0 = blockIdx.x * BM;
    float acc[TM][TN] = {};

    for (int kk = 0; kk < K; kk += BK) {
        #pragma unroll
        for (int it = 0; it < 2; ++it) {
            int r = (tid >> 3) + it * 32;      // 0..63
            int c4 = (tid & 7) * 4;            // 0..28
            int gr = m0 + r;
            float4 v = make_float4(0.f, 0.f, 0.f, 0.f);
            if (gr < n_rows) v = *(const float4*)&A[(size_t)gr * K + kk + c4];
            As[c4 + 0][r] = v.x; As[c4 + 1][r] = v.y;
            As[c4 + 2][r] = v.z; As[c4 + 3][r] = v.w;
        }
        #pragma unroll
        for (int it = 0; it < COUT / 32; ++it) {
            int c = (tid >> 3) + it * 32;      // 0..COUT-1
            int k4 = (tid & 7) * 4;
            const float* Wp = (c < COUT / 2) ? &W0[(size_t)c * K] : &W1[(size_t)(c - COUT / 2) * K];
            float4 v = *(const float4*)&Wp[kk + k4];
            Ws[k4 + 0][c] = v.x; Ws[k4 + 1][c] = v.y;
            Ws[k4 + 2][c] = v.z; Ws[k4 + 3][c] = v.w;
        }
        __syncthreads();
        #pragma unroll
        for (int k = 0; k < BK; ++k) {
            float a[TM], w[TN];
            #pragma unroll
            for (int i = 0; i < TM; ++i) a[i] = As[k][tr * TM + i];
            #pragma unroll
            for (int j = 0; j < TN; ++j) w[j] = Ws[k][j * 32 + tc];
            #pragma unroll
            for (int i = 0; i < TM; ++i)
                #pragma unroll
                for (int j = 0; j < TN; ++j) acc[i][j] += a[i] * w[j];
        }
        __syncthreads();
    }
    #pragma unroll
    for (int i = 0; i < TM; ++i) {
        int gr = m0 + tr * TM + i;
        if (gr >= n_rows) break;
        #pragma unroll
        for (int j = 0; j < TN; ++j) {
            int c = j * 32 + tc;
            float b = (c < COUT / 2) ? B0[c] : B1[c - COUT / 2];
            out[(size_t)gr * COUT + c] = acc[i][j] + b;
        }
    }
}

// ---------------- conv1 edge phase: logits (edge-parallel) + aggregate (node-parallel) --------

__global__ __launch_bounds__(256) void logits1(const float* __restrict__ buf,
                                               const int* __restrict__ adj,
                                               const int* __restrict__ adjd,
                                               const float* __restrict__ att,   // [128]
                                               float* __restrict__ w0, float* __restrict__ w1,
                                               int T) {
    int t = blockIdx.x * 256 + threadIdx.x;
    if (t >= T) return;
    int src = adj[t], dst = adjd[t];
    const float4* xl = (const float4*)&buf[(size_t)src * 256];
    const float4* xr = (const float4*)&buf[(size_t)dst * 256 + 128];
    const float4* a4 = (const float4*)att;   // wave-uniform -> scalar loads
    float s0 = 0.f, s1 = 0.f;
    #pragma unroll
    for (int k = 0; k < 16; ++k) {
        float4 l = xl[k], r = xr[k], a = a4[k];
        s0 += a.x * lrelu(l.x + r.x, ATT_SLOPE) + a.y * lrelu(l.y + r.y, ATT_SLOPE)
            + a.z * lrelu(l.z + r.z, ATT_SLOPE) + a.w * lrelu(l.w + r.w, ATT_SLOPE);
    }
    #pragma unroll
    for (int k = 16; k < 32; ++k) {
        float4 l = xl[k], r = xr[k], a = a4[k];
        s1 += a.x * lrelu(l.x + r.x, ATT_SLOPE) + a.y * lrelu(l.y + r.y, ATT_SLOPE)
            + a.z * lrelu(l.z + r.z, ATT_SLOPE) + a.w * lrelu(l.w + r.w, ATT_SLOPE);
    }
    w0[t] = __expf(s0);
    w1[t] = __expf(s1);
}

// One wave per node, single pass: unnormalized accumulate + lane-local denominator
// (w[j] is lane-uniform so the denom needs no cross-lane reduction), divide at the end.
// Manual 4-way unroll -> 4 independent gather chains in flight.
__global__ __launch_bounds__(256) void agg1(const float* __restrict__ buf,
                                            const int* __restrict__ rowptr,
                                            const int* __restrict__ adj,
                                            const float* __restrict__ w0,
                                            const float* __restrict__ w1,
                                            const float* __restrict__ bias,  // [128]
                                            float* __restrict__ h1, int n) {
    int wid = threadIdx.x >> 6, lane = threadIdx.x & 63;
    int node = blockIdx.x * 4 + wid;
    if (node >= n) return;
    const int s = rowptr[node], e = rowptr[node + 1];
    const float* wsel = (lane < 32) ? w0 : w1;     // lane's head

    float2 a0 = {0.f, 0.f}, a1 = {0.f, 0.f}, a2 = {0.f, 0.f}, a3 = {0.f, 0.f};
    float d0 = 0.f, d1 = 0.f, d2 = 0.f, d3 = 0.f;
    int j = s;
    for (; j + 3 < e; j += 4) {
        int s0 = adj[j], s1 = adj[j + 1], s2 = adj[j + 2], s3 = adj[j + 3];
        float q0 = wsel[j], q1 = wsel[j + 1], q2 = wsel[j + 2], q3 = wsel[j + 3];
        float2 v0 = *(const float2*)&buf[(size_t)s0 * 256 + lane * 2];
        float2 v1 = *(const float2*)&buf[(size_t)s1 * 256 + lane * 2];
        float2 v2 = *(const float2*)&buf[(size_t)s2 * 256 + lane * 2];
        float2 v3 = *(const float2*)&buf[(size_t)s3 * 256 + lane * 2];
        a0.x += q0 * v0.x; a0.y += q0 * v0.y; d0 += q0;
        a1.x += q1 * v1.x; a1.y += q1 * v1.y; d1 += q1;
        a2.x += q2 * v2.x; a2.y += q2 * v2.y; d2 += q2;
        a3.x += q3 * v3.x; a3.y += q3 * v3.y; d3 += q3;
    }
    for (; j < e; ++j) {
        int s0 = adj[j];
        float q0 = wsel[j];
        float2 v0 = *(const float2*)&buf[(size_t)s0 * 256 + lane * 2];
        a0.x += q0 * v0.x; a0.y += q0 * v0.y; d0 += q0;
    }
    float inv = 1.f / (d0 + d1 + d2 + d3);
    float2 acc;
    acc.x = (a0.x + a1.x + a2.x + a3.x) * inv;
    acc.y = (a0.y + a1.y + a2.y + a3.y) * inv;
    float2 b = *(const float2*)&bias[lane * 2];
    float2 o;
    o.x = lrelu(acc.x + b.x, ACT_SLOPE);
    o.y = lrelu(acc.y + b.y, ACT_SLOPE);
    *(float2*)&h1[(size_t)node * 128 + lane * 2] = o;
}

// ---------------- conv2 edge phase (heads=1, ch=64): buf [N,128] = xl(64) | xr(64) ------------

__global__ __launch_bounds__(256) void logits2(const float* __restrict__ buf,
                                               const int* __restrict__ adj,
                                               const int* __restrict__ adjd,
                                               const float* __restrict__ att,   // [64]
                                               float* __restrict__ w0, int T) {
    int t = blockIdx.x * 256 + threadIdx.x;
    if (t >= T) return;
    int src = adj[t], dst = adjd[t];
    const float4* xl = (const float4*)&buf[(size_t)src * 128];
    const float4* xr = (const float4*)&buf[(size_t)dst * 128 + 64];
    const float4* a4 = (const float4*)att;
    float s0 = 0.f;
    #pragma unroll
    for (int k = 0; k < 16; ++k) {
        float4 l = xl[k], r = xr[k], a = a4[k];
        s0 += a.x * lrelu(l.x + r.x, ATT_SLOPE) + a.y * lrelu(l.y + r.y, ATT_SLOPE)
            + a.z * lrelu(l.z + r.z, ATT_SLOPE) + a.w * lrelu(l.w + r.w, ATT_SLOPE);
    }
    w0[t] = __expf(s0);
}

__global__ __launch_bounds__(256) void agg2(const float* __restrict__ buf,
                                            const int* __restrict__ rowptr,
                                            const int* __restrict__ adj,
                                            const float* __restrict__ w0,
                                            const float* __restrict__ bias,  // [64]
                                            float* __restrict__ h2, int n) {
    int wid = threadIdx.x >> 6, lane = threadIdx.x & 63;
    int node = blockIdx.x * 4 + wid;
    if (node >= n) return;
    const int s = rowptr[node], e = rowptr[node + 1];

    float a0 = 0.f, a1 = 0.f, a2 = 0.f, a3 = 0.f;
    float d0 = 0.f, d1 = 0.f, d2 = 0.f, d3 = 0.f;
    int j = s;
    for (; j + 3 < e; j += 4) {
        int s0 = adj[j], s1 = adj[j + 1], s2 = adj[j + 2], s3 = adj[j + 3];
        float q0 = w0[j], q1 = w0[j + 1], q2 = w0[j + 2], q3 = w0[j + 3];
        float v0 = buf[(size_t)s0 * 128 + lane];
        float v1 = buf[(size_t)s1 * 128 + lane];
        float v2 = buf[(size_t)s2 * 128 + lane];
        float v3 = buf[(size_t)s3 * 128 + lane];
        a0 += q0 * v0; d0 += q0;
        a1 += q1 * v1; d1 += q1;
        a2 += q2 * v2; d2 += q2;
        a3 += q3 * v3; d3 += q3;
    }
    for (; j < e; ++j) {
        int s0 = adj[j];
        float q0 = w0[j];
        a0 += q0 * buf[(size_t)s0 * 128 + lane];
        d0 += q0;
    }
    float acc = (a0 + a1 + a2 + a3) / (d0 + d1 + d2 + d3);
    h2[(size_t)node * 64 + lane] = lrelu(acc + bias[lane], ACT_SLOPE);
}

// ---------------- global mean pool (batch sorted) + fc1 + lrelu + fc2 ----------------

__device__ __forceinline__ int lower_bound(const int* a, int n, int v) {
    int lo = 0, hi = n;
    while (lo < hi) { int mid = (lo + hi) >> 1; if (a[mid] < v) lo = mid + 1; else hi = mid; }
    return lo;
}

__global__ __launch_bounds__(256) void pool_mlp(const float* __restrict__ h2,   // [N,64]
                                                const int* __restrict__ batch,  // [N] sorted
                                                const float* __restrict__ fc1_w,
                                                const float* __restrict__ fc1_b,
                                                const float* __restrict__ fc2_w,
                                                const float* __restrict__ fc2_b,
                                                float* __restrict__ out, int n) {
    const int g = blockIdx.x;
    const int tid = threadIdx.x;
    const int c = tid & 63, q = tid >> 6;
    __shared__ float partial[4][64];
    __shared__ float pooled[64];
    __shared__ float hmid[64];

    int lo = lower_bound(batch, n, g);
    int hi = lower_bound(batch, n, g + 1);

    float sum = 0.f;
    for (int i = lo + q; i < hi; i += 4) sum += h2[(size_t)i * 64 + c];
    partial[q][c] = sum;
    __syncthreads();
    if (q == 0) {
        float s = partial[0][c] + partial[1][c] + partial[2][c] + partial[3][c];
        int cnt = hi - lo;
        pooled[c] = s / (float)max(cnt, 1);
    }
    __syncthreads();
    if (tid < 64) {
        float acc = fc1_b[tid];
        const float* w = &fc1_w[(size_t)tid * 64];
        #pragma unroll
        for (int k = 0; k < 64; ++k) acc += pooled[k] * w[k];
        hmid[tid] = lrelu(acc, ACT_SLOPE);
    }
    __syncthreads();
    for (int o = tid; o < 768; o += 256) {
        float acc = fc2_b[o];
        const float* w = &fc2_w[(size_t)o * 64];
        #pragma unroll
        for (int k = 0; k < 64; ++k) acc += hmid[k] * w[k];
        out[(size_t)g * 768 + o] = acc;
    }
}

// ---------------- launch ----------------

extern "C" void kernel_launch(void* const* d_in, const int* in_sizes, int n_in,
                              void* d_out, int out_size, void* d_ws, size_t ws_size,
                              hipStream_t stream) {
    const float* x     = (const float*)d_in[0];
    const int*   ei    = (const int*)d_in[1];
    const int*   batch = (const int*)d_in[2];
    const float* w1_l  = (const float*)d_in[3];
    const float* b1_l  = (const float*)d_in[4];
    const float* w1_r  = (const float*)d_in[5];
    const float* b1_r  = (const float*)d_in[6];
    const float* att1  = (const float*)d_in[7];
    const float* bias1 = (const float*)d_in[8];
    const float* w2_l  = (const float*)d_in[9];
    const float* b2_l  = (const float*)d_in[10];
    const float* w2_r  = (const float*)d_in[11];
    const float* b2_r  = (const float*)d_in[12];
    const float* att2  = (const float*)d_in[13];
    const float* bias2 = (const float*)d_in[14];
    const float* fc1_w = (const float*)d_in[15];
    const float* fc1_b = (const float*)d_in[16];
    const float* fc2_w = (const float*)d_in[17];
    const float* fc2_b = (const float*)d_in[18];
    float* out = (float*)d_out;

    const int N = in_sizes[2];
    const int E = in_sizes[1] / 2;
    const int T = E + N;
    const int G = out_size / 768;

    char* ws = (char*)d_ws;
    size_t off = 0;
    auto alloc = [&](size_t bytes) -> void* {
        void* p = ws + off;
        off = (off + bytes + 255) & ~(size_t)255;
        return p;
    };
    int*   deg    = (int*)alloc((size_t)N * 4);
    int*   rowptr = (int*)alloc((size_t)(N + 1) * 4);
    int*   cursor = (int*)alloc((size_t)N * 4);
    int*   bsum   = (int*)alloc(1024);
    int*   boff   = (int*)alloc(1024);
    int*   adj    = (int*)alloc((size_t)T * 4);
    int*   adjd   = (int*)alloc((size_t)T * 4);
    float* ew0    = (float*)alloc((size_t)T * 4);
    float* ew1    = (float*)alloc((size_t)T * 4);
    float* h1     = (float*)alloc((size_t)N * 128 * 4);
    float* buf1   = (float*)alloc((size_t)N * 256 * 4);
    float* buf2 = buf1;                       // lifetime aliasing
    float* h2   = buf1 + (size_t)N * 128;

    const int nbN  = (N + 255) / 256;
    const int nbT  = (T + 255) / 256;
    const int gemG = (N + 63) / 64;
    const int edgG = (N + 3) / 4;

    hipMemsetAsync(deg, 0, (size_t)N * 4, stream);
    k_count<<<nbT, 256, 0, stream>>>(ei, E, N, deg);
    k_scan_block<<<nbN, 256, 0, stream>>>(deg, N, rowptr + 1, bsum);
    k_scan_bsum<<<1, 256, 0, stream>>>(bsum, nbN, boff);
    k_scan_add<<<nbN, 256, 0, stream>>>(rowptr, boff, N);
    hipMemsetAsync(cursor, 0, (size_t)N * 4, stream);
    k_scatter<<<nbT, 256, 0, stream>>>(ei, E, N, rowptr, cursor, adj, adjd);

    gemm_dual<256><<<gemG, 256, 0, stream>>>(x, N, w1_l, w1_r, b1_l, b1_r, buf1);
    logits1<<<nbT, 256, 0, stream>>>(buf1, adj, adjd, att1, ew0, ew1, T);
    agg1<<<edgG, 256, 0, stream>>>(buf1, rowptr, adj, ew0, ew1, bias1, h1, N);

    gemm_dual<128><<<gemG, 256, 0, stream>>>(h1, N, w2_l, w2_r, b2_l, b2_r, buf2);
    logits2<<<nbT, 256, 0, stream>>>(buf2, adj, adjd, att2, ew0, T);
    agg2<<<edgG, 256, 0, stream>>>(buf2, rowptr, adj, ew0, bias2, h2, N);

    pool_mlp<<<G, 256, 0, stream>>>(h2, batch, fc1_w, fc1_b, fc2_w, fc2_b, out, N);
}

// Round 4
// 555.027 us; speedup vs baseline: 1.3285x; 1.0413x over previous
//
#include <hip/hip_runtime.h>

#define ATT_SLOPE 0.2f
#define ACT_SLOPE 0.01f

typedef _Float16 half8  __attribute__((ext_vector_type(8)));
typedef _Float16 half4v __attribute__((ext_vector_type(4)));
typedef _Float16 half2v __attribute__((ext_vector_type(2)));
typedef float    floatx4 __attribute__((ext_vector_type(4)));

__device__ __forceinline__ float lrelu(float v, float s) {
    return fmaxf(v, v * s);
}

// ---------------- CSR build (edges grouped by dst, self loops appended) ----------------

__global__ __launch_bounds__(256) void k_count(const int* __restrict__ ei, int E, int N,
                                               int* __restrict__ deg) {
    int i = blockIdx.x * 256 + threadIdx.x;
    int total = E + N;
    if (i >= total) return;
    int dst = (i < E) ? ei[E + i] : (i - E);
    atomicAdd(&deg[dst], 1);
}

__global__ __launch_bounds__(256) void k_scan_block(const int* __restrict__ deg, int n,
                                                    int* __restrict__ rp1, int* __restrict__ bsum) {
    __shared__ int s[256];
    int tid = threadIdx.x;
    int i = blockIdx.x * 256 + tid;
    s[tid] = (i < n) ? deg[i] : 0;
    __syncthreads();
    for (int off = 1; off < 256; off <<= 1) {
        int t = (tid >= off) ? s[tid - off] : 0;
        __syncthreads();
        s[tid] += t;
        __syncthreads();
    }
    if (i < n) rp1[i] = s[tid];
    if (tid == 255) bsum[blockIdx.x] = s[255];
}

__global__ __launch_bounds__(256) void k_scan_bsum(const int* __restrict__ bsum, int nb,
                                                   int* __restrict__ boff) {
    __shared__ int s[256];
    int tid = threadIdx.x;
    s[tid] = (tid < nb) ? bsum[tid] : 0;
    __syncthreads();
    for (int off = 1; off < 256; off <<= 1) {
        int t = (tid >= off) ? s[tid - off] : 0;
        __syncthreads();
        s[tid] += t;
        __syncthreads();
    }
    if (tid < nb) boff[tid] = (tid > 0) ? s[tid - 1] : 0;
}

__global__ __launch_bounds__(256) void k_scan_add(int* __restrict__ rowptr,
                                                  const int* __restrict__ boff, int n) {
    int i = blockIdx.x * 256 + threadIdx.x;
    if (i < n) rowptr[i + 1] += boff[blockIdx.x];
    if (i == 0) rowptr[0] = 0;
}

__global__ __launch_bounds__(256) void k_scatter(const int* __restrict__ ei, int E, int N,
                                                 const int* __restrict__ rowptr,
                                                 int* __restrict__ cursor,
                                                 int* __restrict__ adj, int* __restrict__ adjd) {
    int i = blockIdx.x * 256 + threadIdx.x;
    int total = E + N;
    if (i >= total) return;
    int src, dst;
    if (i < E) { src = ei[i]; dst = ei[E + i]; } else { src = i - E; dst = i - E; }
    int pos = atomicAdd(&cursor[dst], 1);
    int p = rowptr[dst] + pos;
    adj[p] = src;
    adjd[p] = dst;
}

// ---------------- fp32 -> (hi,lo) fp16 split encodes ----------------

__global__ __launch_bounds__(256) void k_encode4(const float* __restrict__ in,
                                                 _Float16* __restrict__ hi,
                                                 _Float16* __restrict__ lo, int n4) {
    int i = blockIdx.x * 256 + threadIdx.x;
    if (i >= n4) return;
    float4 v = ((const float4*)in)[i];
    half4v h, l;
    h[0] = (_Float16)v.x; l[0] = (_Float16)(v.x - (float)h[0]);
    h[1] = (_Float16)v.y; l[1] = (_Float16)(v.y - (float)h[1]);
    h[2] = (_Float16)v.z; l[2] = (_Float16)(v.z - (float)h[2]);
    h[3] = (_Float16)v.w; l[3] = (_Float16)(v.w - (float)h[3]);
    ((half4v*)hi)[i] = h;
    ((half4v*)lo)[i] = l;
}

// all four weight matrices in one launch: W1 = [w1_l ; w1_r] (256x128), W2 = [w2_l ; w2_r] (128x128)
__global__ __launch_bounds__(256) void k_encode_w(const float* __restrict__ w1l,
                                                  const float* __restrict__ w1r,
                                                  const float* __restrict__ w2l,
                                                  const float* __restrict__ w2r,
                                                  _Float16* __restrict__ W1h,
                                                  _Float16* __restrict__ W1lo,
                                                  _Float16* __restrict__ W2h,
                                                  _Float16* __restrict__ W2lo) {
    int i = blockIdx.x * 256 + threadIdx.x;   // 0 .. 49151
    if (i >= 49152) return;
    float v;
    _Float16 *ph, *pl;
    int idx;
    if (i < 32768) {
        idx = i;
        v = (i < 16384) ? w1l[i] : w1r[i - 16384];
        ph = W1h; pl = W1lo;
    } else {
        int j = i - 32768;
        idx = j;
        v = (j < 8192) ? w2l[j] : w2r[j - 8192];
        ph = W2h; pl = W2lo;
    }
    _Float16 h = (_Float16)v;
    ph[idx] = h;
    pl[idx] = (_Float16)(v - (float)h);
}

// ---------------- MFMA split-f16 dual linear ----------------
// out[n, COUT] = [A @ W0^T + b0 | A @ W1^T + b1], A in hi/lo fp16 [n,128], W in hi/lo fp16 [COUT,128].
// a*w ~= ah*wh + al*wh + ah*wl  (residual al*wl ~ 2^-22 relative).
// No LDS, no barriers: each lane's MFMA fragment is one contiguous 16B global load.
// Wave = 16 rows x COUT cols; block = 4 waves = 64 rows.

template <int COUT>
__global__ __launch_bounds__(256) void gemm_mfma(const _Float16* __restrict__ Ahi,
                                                 const _Float16* __restrict__ Alo, int n_rows,
                                                 const _Float16* __restrict__ Whi,
                                                 const _Float16* __restrict__ Wlo,
                                                 const float* __restrict__ B0,
                                                 const float* __restrict__ B1,
                                                 float* __restrict__ out) {
    constexpr int NT = COUT / 16;
    const int lane = threadIdx.x & 63;
    const int wv = threadIdx.x >> 6;
    const int m = lane & 15, q = lane >> 4;
    const long row0 = ((long)blockIdx.x * 4 + wv) * 16;
    if (row0 >= n_rows) return;           // wave-uniform guard (n_rows % 16 == 0)
    const long arow = row0 + m;

    floatx4 acc[NT] = {};
    for (int kk = 0; kk < 128; kk += 32) {
        half8 ah = *(const half8*)&Ahi[(size_t)arow * 128 + kk + q * 8];
        half8 al = *(const half8*)&Alo[(size_t)arow * 128 + kk + q * 8];
        #pragma unroll
        for (int nt = 0; nt < NT; ++nt) {
            size_t wo = (size_t)(nt * 16 + m) * 128 + kk + q * 8;
            half8 bh = *(const half8*)&Whi[wo];
            half8 bl = *(const half8*)&Wlo[wo];
            acc[nt] = __builtin_amdgcn_mfma_f32_16x16x32_f16(ah, bh, acc[nt], 0, 0, 0);
            acc[nt] = __builtin_amdgcn_mfma_f32_16x16x32_f16(al, bh, acc[nt], 0, 0, 0);
            acc[nt] = __builtin_amdgcn_mfma_f32_16x16x32_f16(ah, bl, acc[nt], 0, 0, 0);
        }
    }
    // C/D layout: col = lane&15, row = (lane>>4)*4 + reg
    #pragma unroll
    for (int nt = 0; nt < NT; ++nt) {
        int col = nt * 16 + m;
        float b = (col < COUT / 2) ? B0[col] : B1[col - COUT / 2];
        #pragma unroll
        for (int r = 0; r < 4; ++r) {
            long grow = row0 + q * 4 + r;
            out[(size_t)grow * COUT + col] = acc[nt][r] + b;
        }
    }
}

// ---------------- conv1 edge phase: logits (edge-parallel) + aggregate (node-parallel) --------

__global__ __launch_bounds__(256) void logits1(const float* __restrict__ buf,
                                               const int* __restrict__ adj,
                                               const int* __restrict__ adjd,
                                               const float* __restrict__ att,   // [128]
                                               float* __restrict__ w0, float* __restrict__ w1,
                                               int T) {
    int t = blockIdx.x * 256 + threadIdx.x;
    if (t >= T) return;
    int src = adj[t], dst = adjd[t];
    const float4* xl = (const float4*)&buf[(size_t)src * 256];
    const float4* xr = (const float4*)&buf[(size_t)dst * 256 + 128];
    const float4* a4 = (const float4*)att;
    float s0 = 0.f, s1 = 0.f;
    #pragma unroll
    for (int k = 0; k < 16; ++k) {
        float4 l = xl[k], r = xr[k], a = a4[k];
        s0 += a.x * lrelu(l.x + r.x, ATT_SLOPE) + a.y * lrelu(l.y + r.y, ATT_SLOPE)
            + a.z * lrelu(l.z + r.z, ATT_SLOPE) + a.w * lrelu(l.w + r.w, ATT_SLOPE);
    }
    #pragma unroll
    for (int k = 16; k < 32; ++k) {
        float4 l = xl[k], r = xr[k], a = a4[k];
        s1 += a.x * lrelu(l.x + r.x, ATT_SLOPE) + a.y * lrelu(l.y + r.y, ATT_SLOPE)
            + a.z * lrelu(l.z + r.z, ATT_SLOPE) + a.w * lrelu(l.w + r.w, ATT_SLOPE);
    }
    w0[t] = __expf(s0);
    w1[t] = __expf(s1);
}

// One wave per node, single pass; outputs h1 as hi/lo fp16 (input to gemm2).
__global__ __launch_bounds__(256) void agg1(const float* __restrict__ buf,
                                            const int* __restrict__ rowptr,
                                            const int* __restrict__ adj,
                                            const float* __restrict__ w0,
                                            const float* __restrict__ w1,
                                            const float* __restrict__ bias,   // [128]
                                            _Float16* __restrict__ h1hi,
                                            _Float16* __restrict__ h1lo, int n) {
    int wid = threadIdx.x >> 6, lane = threadIdx.x & 63;
    int node = blockIdx.x * 4 + wid;
    if (node >= n) return;
    const int s = rowptr[node], e = rowptr[node + 1];
    const float* wsel = (lane < 32) ? w0 : w1;

    float2 a0 = {0.f, 0.f}, a1 = {0.f, 0.f}, a2 = {0.f, 0.f}, a3 = {0.f, 0.f};
    float d0 = 0.f, d1 = 0.f, d2 = 0.f, d3 = 0.f;
    int j = s;
    for (; j + 3 < e; j += 4) {
        int s0 = adj[j], s1 = adj[j + 1], s2 = adj[j + 2], s3 = adj[j + 3];
        float q0 = wsel[j], q1 = wsel[j + 1], q2 = wsel[j + 2], q3 = wsel[j + 3];
        float2 v0 = *(const float2*)&buf[(size_t)s0 * 256 + lane * 2];
        float2 v1 = *(const float2*)&buf[(size_t)s1 * 256 + lane * 2];
        float2 v2 = *(const float2*)&buf[(size_t)s2 * 256 + lane * 2];
        float2 v3 = *(const float2*)&buf[(size_t)s3 * 256 + lane * 2];
        a0.x += q0 * v0.x; a0.y += q0 * v0.y; d0 += q0;
        a1.x += q1 * v1.x; a1.y += q1 * v1.y; d1 += q1;
        a2.x += q2 * v2.x; a2.y += q2 * v2.y; d2 += q2;
        a3.x += q3 * v3.x; a3.y += q3 * v3.y; d3 += q3;
    }
    for (; j < e; ++j) {
        int s0 = adj[j];
        float q0 = wsel[j];
        float2 v0 = *(const float2*)&buf[(size_t)s0 * 256 + lane * 2];
        a0.x += q0 * v0.x; a0.y += q0 * v0.y; d0 += q0;
    }
    float inv = 1.f / (d0 + d1 + d2 + d3);
    float2 b = *(const float2*)&bias[lane * 2];
    float ox = lrelu((a0.x + a1.x + a2.x + a3.x) * inv + b.x, ACT_SLOPE);
    float oy = lrelu((a0.y + a1.y + a2.y + a3.y) * inv + b.y, ACT_SLOPE);
    half2v hv, lv;
    hv[0] = (_Float16)ox; lv[0] = (_Float16)(ox - (float)hv[0]);
    hv[1] = (_Float16)oy; lv[1] = (_Float16)(oy - (float)hv[1]);
    *(half2v*)&h1hi[(size_t)node * 128 + lane * 2] = hv;
    *(half2v*)&h1lo[(size_t)node * 128 + lane * 2] = lv;
}

// ---------------- conv2 edge phase (heads=1, ch=64): buf [N,128] = xl(64) | xr(64) ------------

__global__ __launch_bounds__(256) void logits2(const float* __restrict__ buf,
                                               const int* __restrict__ adj,
                                               const int* __restrict__ adjd,
                                               const float* __restrict__ att,   // [64]
                                               float* __restrict__ w0, int T) {
    int t = blockIdx.x * 256 + threadIdx.x;
    if (t >= T) return;
    int src = adj[t], dst = adjd[t];
    const float4* xl = (const float4*)&buf[(size_t)src * 128];
    const float4* xr = (const float4*)&buf[(size_t)dst * 128 + 64];
    const float4* a4 = (const float4*)att;
    float s0 = 0.f;
    #pragma unroll
    for (int k = 0; k < 16; ++k) {
        float4 l = xl[k], r = xr[k], a = a4[k];
        s0 += a.x * lrelu(l.x + r.x, ATT_SLOPE) + a.y * lrelu(l.y + r.y, ATT_SLOPE)
            + a.z * lrelu(l.z + r.z, ATT_SLOPE) + a.w * lrelu(l.w + r.w, ATT_SLOPE);
    }
    w0[t] = __expf(s0);
}

__global__ __launch_bounds__(256) void agg2(const float* __restrict__ buf,
                                            const int* __restrict__ rowptr,
                                            const int* __restrict__ adj,
                                            const float* __restrict__ w0,
                                            const float* __restrict__ bias,  // [64]
                                            float* __restrict__ h2, int n) {
    int wid = threadIdx.x >> 6, lane = threadIdx.x & 63;
    int node = blockIdx.x * 4 + wid;
    if (node >= n) return;
    const int s = rowptr[node], e = rowptr[node + 1];

    float a0 = 0.f, a1 = 0.f, a2 = 0.f, a3 = 0.f;
    float d0 = 0.f, d1 = 0.f, d2 = 0.f, d3 = 0.f;
    int j = s;
    for (; j + 3 < e; j += 4) {
        int s0 = adj[j], s1 = adj[j + 1], s2 = adj[j + 2], s3 = adj[j + 3];
        float q0 = w0[j], q1 = w0[j + 1], q2 = w0[j + 2], q3 = w0[j + 3];
        float v0 = buf[(size_t)s0 * 128 + lane];
        float v1 = buf[(size_t)s1 * 128 + lane];
        float v2 = buf[(size_t)s2 * 128 + lane];
        float v3 = buf[(size_t)s3 * 128 + lane];
        a0 += q0 * v0; d0 += q0;
        a1 += q1 * v1; d1 += q1;
        a2 += q2 * v2; d2 += q2;
        a3 += q3 * v3; d3 += q3;
    }
    for (; j < e; ++j) {
        int s0 = adj[j];
        float q0 = w0[j];
        a0 += q0 * buf[(size_t)s0 * 128 + lane];
        d0 += q0;
    }
    float acc = (a0 + a1 + a2 + a3) / (d0 + d1 + d2 + d3);
    h2[(size_t)node * 64 + lane] = lrelu(acc + bias[lane], ACT_SLOPE);
}

// ---------------- global mean pool (batch sorted) + fc1 + lrelu + fc2 ----------------

__device__ __forceinline__ int lower_bound(const int* a, int n, int v) {
    int lo = 0, hi = n;
    while (lo < hi) { int mid = (lo + hi) >> 1; if (a[mid] < v) lo = mid + 1; else hi = mid; }
    return lo;
}

__global__ __launch_bounds__(256) void pool_mlp(const float* __restrict__ h2,   // [N,64]
                                                const int* __restrict__ batch,  // [N] sorted
                                                const float* __restrict__ fc1_w,
                                                const float* __restrict__ fc1_b,
                                                const float* __restrict__ fc2_w,
                                                const float* __restrict__ fc2_b,
                                                float* __restrict__ out, int n) {
    const int g = blockIdx.x;
    const int tid = threadIdx.x;
    const int c = tid & 63, q = tid >> 6;
    __shared__ float partial[4][64];
    __shared__ float pooled[64];
    __shared__ float hmid[64];

    int lo = lower_bound(batch, n, g);
    int hi = lower_bound(batch, n, g + 1);

    float sum = 0.f;
    for (int i = lo + q; i < hi; i += 4) sum += h2[(size_t)i * 64 + c];
    partial[q][c] = sum;
    __syncthreads();
    if (q == 0) {
        float s = partial[0][c] + partial[1][c] + partial[2][c] + partial[3][c];
        int cnt = hi - lo;
        pooled[c] = s / (float)max(cnt, 1);
    }
    __syncthreads();
    if (tid < 64) {
        float acc = fc1_b[tid];
        const float* w = &fc1_w[(size_t)tid * 64];
        #pragma unroll
        for (int k = 0; k < 64; ++k) acc += pooled[k] * w[k];
        hmid[tid] = lrelu(acc, ACT_SLOPE);
    }
    __syncthreads();
    for (int o = tid; o < 768; o += 256) {
        float acc = fc2_b[o];
        const float* w = &fc2_w[(size_t)o * 64];
        #pragma unroll
        for (int k = 0; k < 64; ++k) acc += hmid[k] * w[k];
        out[(size_t)g * 768 + o] = acc;
    }
}

// ---------------- launch ----------------

extern "C" void kernel_launch(void* const* d_in, const int* in_sizes, int n_in,
                              void* d_out, int out_size, void* d_ws, size_t ws_size,
                              hipStream_t stream) {
    const float* x     = (const float*)d_in[0];
    const int*   ei    = (const int*)d_in[1];
    const int*   batch = (const int*)d_in[2];
    const float* w1_l  = (const float*)d_in[3];
    const float* b1_l  = (const float*)d_in[4];
    const float* w1_r  = (const float*)d_in[5];
    const float* b1_r  = (const float*)d_in[6];
    const float* att1  = (const float*)d_in[7];
    const float* bias1 = (const float*)d_in[8];
    const float* w2_l  = (const float*)d_in[9];
    const float* b2_l  = (const float*)d_in[10];
    const float* w2_r  = (const float*)d_in[11];
    const float* b2_r  = (const float*)d_in[12];
    const float* att2  = (const float*)d_in[13];
    const float* bias2 = (const float*)d_in[14];
    const float* fc1_w = (const float*)d_in[15];
    const float* fc1_b = (const float*)d_in[16];
    const float* fc2_w = (const float*)d_in[17];
    const float* fc2_b = (const float*)d_in[18];
    float* out = (float*)d_out;

    const int N = in_sizes[2];
    const int E = in_sizes[1] / 2;
    const int T = E + N;
    const int G = out_size / 768;

    char* ws = (char*)d_ws;
    size_t off = 0;
    auto alloc = [&](size_t bytes) -> void* {
        void* p = ws + off;
        off = (off + bytes + 255) & ~(size_t)255;
        return p;
    };
    int*      deg    = (int*)alloc((size_t)N * 4);
    int*      rowptr = (int*)alloc((size_t)(N + 1) * 4);
    int*      cursor = (int*)alloc((size_t)N * 4);
    int*      bsum   = (int*)alloc(1024);
    int*      boff   = (int*)alloc(1024);
    int*      adj    = (int*)alloc((size_t)T * 4);
    int*      adjd   = (int*)alloc((size_t)T * 4);
    float*    ew0    = (float*)alloc((size_t)T * 4);
    float*    ew1    = (float*)alloc((size_t)T * 4);
    _Float16* xhi    = (_Float16*)alloc((size_t)N * 128 * 2);
    _Float16* xlo    = (_Float16*)alloc((size_t)N * 128 * 2);
    _Float16* W1h    = (_Float16*)alloc(32768 * 2);
    _Float16* W1lo   = (_Float16*)alloc(32768 * 2);
    _Float16* W2h    = (_Float16*)alloc(16384 * 2);
    _Float16* W2lo   = (_Float16*)alloc(16384 * 2);
    float*    buf1   = (float*)alloc((size_t)N * 256 * 4);
    // lifetime aliasing: xhi/xlo dead after gemm1 -> reuse for h1 hi/lo;
    // buf1 dead after agg1 -> reuse for buf2 and h2.
    _Float16* h1hi = xhi;
    _Float16* h1lo = xlo;
    float*    buf2 = buf1;                    // [N,128]
    float*    h2   = buf1 + (size_t)N * 128;  // [N,64]

    const int nbN  = (N + 255) / 256;
    const int nbT  = (T + 255) / 256;
    const int mfmG = (N + 63) / 64;
    const int edgG = (N + 3) / 4;
    const int encG = ((N * 128 / 4) + 255) / 256;

    // ---- CSR build ----
    hipMemsetAsync(deg, 0, (size_t)N * 4, stream);
    k_count<<<nbT, 256, 0, stream>>>(ei, E, N, deg);
    k_scan_block<<<nbN, 256, 0, stream>>>(deg, N, rowptr + 1, bsum);
    k_scan_bsum<<<1, 256, 0, stream>>>(bsum, nbN, boff);
    k_scan_add<<<nbN, 256, 0, stream>>>(rowptr, boff, N);
    hipMemsetAsync(cursor, 0, (size_t)N * 4, stream);
    k_scatter<<<nbT, 256, 0, stream>>>(ei, E, N, rowptr, cursor, adj, adjd);

    // ---- encodes ----
    k_encode_w<<<192, 256, 0, stream>>>(w1_l, w1_r, w2_l, w2_r, W1h, W1lo, W2h, W2lo);
    k_encode4<<<encG, 256, 0, stream>>>(x, xhi, xlo, N * 128 / 4);

    // ---- conv1 ----
    gemm_mfma<256><<<mfmG, 256, 0, stream>>>(xhi, xlo, N, W1h, W1lo, b1_l, b1_r, buf1);
    logits1<<<nbT, 256, 0, stream>>>(buf1, adj, adjd, att1, ew0, ew1, T);
    agg1<<<edgG, 256, 0, stream>>>(buf1, rowptr, adj, ew0, ew1, bias1, h1hi, h1lo, N);

    // ---- conv2 ----
    gemm_mfma<128><<<mfmG, 256, 0, stream>>>(h1hi, h1lo, N, W2h, W2lo, b2_l, b2_r, buf2);
    logits2<<<nbT, 256, 0, stream>>>(buf2, adj, adjd, att2, ew0, T);
    agg2<<<edgG, 256, 0, stream>>>(buf2, rowptr, adj, ew0, bias2, h2, N);

    // ---- pool + MLP head ----
    pool_mlp<<<G, 256, 0, stream>>>(h2, batch, fc1_w, fc1_b, fc2_w, fc2_b, out, N);
}

// Round 5
// 494.838 us; speedup vs baseline: 1.4901x; 1.1216x over previous
//
#include <hip/hip_runtime.h>

#define ATT_SLOPE 0.2f
#define ACT_SLOPE 0.01f

typedef _Float16 half8  __attribute__((ext_vector_type(8)));
typedef _Float16 half4v __attribute__((ext_vector_type(4)));
typedef _Float16 half2v __attribute__((ext_vector_type(2)));
typedef float    floatx4 __attribute__((ext_vector_type(4)));

__device__ __forceinline__ float lrelu(float v, float s) {
    return fmaxf(v, v * s);
}

// ---------------- CSR build (edges grouped by dst, self loops appended) ----------------

__global__ __launch_bounds__(256) void k_count(const int* __restrict__ ei, int E, int N,
                                               int* __restrict__ deg) {
    int i = blockIdx.x * 256 + threadIdx.x;
    int total = E + N;
    if (i >= total) return;
    int dst = (i < E) ? ei[E + i] : (i - E);
    atomicAdd(&deg[dst], 1);
}

__global__ __launch_bounds__(256) void k_scan_block(const int* __restrict__ deg, int n,
                                                    int* __restrict__ rp1, int* __restrict__ bsum) {
    __shared__ int s[256];
    int tid = threadIdx.x;
    int i = blockIdx.x * 256 + tid;
    s[tid] = (i < n) ? deg[i] : 0;
    __syncthreads();
    for (int off = 1; off < 256; off <<= 1) {
        int t = (tid >= off) ? s[tid - off] : 0;
        __syncthreads();
        s[tid] += t;
        __syncthreads();
    }
    if (i < n) rp1[i] = s[tid];
    if (tid == 255) bsum[blockIdx.x] = s[255];
}

__global__ __launch_bounds__(256) void k_scan_bsum(const int* __restrict__ bsum, int nb,
                                                   int* __restrict__ boff) {
    __shared__ int s[256];
    int tid = threadIdx.x;
    s[tid] = (tid < nb) ? bsum[tid] : 0;
    __syncthreads();
    for (int off = 1; off < 256; off <<= 1) {
        int t = (tid >= off) ? s[tid - off] : 0;
        __syncthreads();
        s[tid] += t;
        __syncthreads();
    }
    if (tid < nb) boff[tid] = (tid > 0) ? s[tid - 1] : 0;
}

__global__ __launch_bounds__(256) void k_scan_add(int* __restrict__ rowptr,
                                                  const int* __restrict__ boff, int n) {
    int i = blockIdx.x * 256 + threadIdx.x;
    if (i < n) rowptr[i + 1] += boff[blockIdx.x];
    if (i == 0) rowptr[0] = 0;
}

__global__ __launch_bounds__(256) void k_scatter(const int* __restrict__ ei, int E, int N,
                                                 const int* __restrict__ rowptr,
                                                 int* __restrict__ cursor,
                                                 int* __restrict__ adj, int* __restrict__ adjd) {
    int i = blockIdx.x * 256 + threadIdx.x;
    int total = E + N;
    if (i >= total) return;
    int src, dst;
    if (i < E) { src = ei[i]; dst = ei[E + i]; } else { src = i - E; dst = i - E; }
    int pos = atomicAdd(&cursor[dst], 1);
    int p = rowptr[dst] + pos;
    adj[p] = src;
    adjd[p] = dst;
}

// ---------------- fp32 -> (hi,lo) fp16 split encodes ----------------

__global__ __launch_bounds__(256) void k_encode4(const float* __restrict__ in,
                                                 _Float16* __restrict__ hi,
                                                 _Float16* __restrict__ lo, int n4) {
    int i = blockIdx.x * 256 + threadIdx.x;
    if (i >= n4) return;
    float4 v = ((const float4*)in)[i];
    half4v h, l;
    h[0] = (_Float16)v.x; l[0] = (_Float16)(v.x - (float)h[0]);
    h[1] = (_Float16)v.y; l[1] = (_Float16)(v.y - (float)h[1]);
    h[2] = (_Float16)v.z; l[2] = (_Float16)(v.z - (float)h[2]);
    h[3] = (_Float16)v.w; l[3] = (_Float16)(v.w - (float)h[3]);
    ((half4v*)hi)[i] = h;
    ((half4v*)lo)[i] = l;
}

// all four weight matrices in one launch: W1 = [w1_l ; w1_r] (256x128), W2 = [w2_l ; w2_r] (128x128)
__global__ __launch_bounds__(256) void k_encode_w(const float* __restrict__ w1l,
                                                  const float* __restrict__ w1r,
                                                  const float* __restrict__ w2l,
                                                  const float* __restrict__ w2r,
                                                  _Float16* __restrict__ W1h,
                                                  _Float16* __restrict__ W1lo,
                                                  _Float16* __restrict__ W2h,
                                                  _Float16* __restrict__ W2lo) {
    int i = blockIdx.x * 256 + threadIdx.x;   // 0 .. 49151
    if (i >= 49152) return;
    float v;
    _Float16 *ph, *pl;
    int idx;
    if (i < 32768) {
        idx = i;
        v = (i < 16384) ? w1l[i] : w1r[i - 16384];
        ph = W1h; pl = W1lo;
    } else {
        int j = i - 32768;
        idx = j;
        v = (j < 8192) ? w2l[j] : w2r[j - 8192];
        ph = W2h; pl = W2lo;
    }
    _Float16 h = (_Float16)v;
    ph[idx] = h;
    pl[idx] = (_Float16)(v - (float)h);
}

// ---------------- MFMA split-f16 dual linear, fp16 output ----------------
// out[n, COUT] = [A @ W0^T + b0 | A @ W1^T + b1], computed a*w ~= ah*wh + al*wh + ah*wl,
// accumulated fp32, stored as fp16 (edge phase consumes fp16).
// No LDS, no barriers: each lane's MFMA fragment is one contiguous 16B global load.

template <int COUT>
__global__ __launch_bounds__(256) void gemm_mfma(const _Float16* __restrict__ Ahi,
                                                 const _Float16* __restrict__ Alo, int n_rows,
                                                 const _Float16* __restrict__ Whi,
                                                 const _Float16* __restrict__ Wlo,
                                                 const float* __restrict__ B0,
                                                 const float* __restrict__ B1,
                                                 _Float16* __restrict__ out) {
    constexpr int NT = COUT / 16;
    const int lane = threadIdx.x & 63;
    const int wv = threadIdx.x >> 6;
    const int m = lane & 15, q = lane >> 4;
    const long row0 = ((long)blockIdx.x * 4 + wv) * 16;
    if (row0 >= n_rows) return;           // wave-uniform guard
    const long arow = row0 + m;

    floatx4 acc[NT] = {};
    for (int kk = 0; kk < 128; kk += 32) {
        half8 ah = *(const half8*)&Ahi[(size_t)arow * 128 + kk + q * 8];
        half8 al = *(const half8*)&Alo[(size_t)arow * 128 + kk + q * 8];
        #pragma unroll
        for (int nt = 0; nt < NT; ++nt) {
            size_t wo = (size_t)(nt * 16 + m) * 128 + kk + q * 8;
            half8 bh = *(const half8*)&Whi[wo];
            half8 bl = *(const half8*)&Wlo[wo];
            acc[nt] = __builtin_amdgcn_mfma_f32_16x16x32_f16(ah, bh, acc[nt], 0, 0, 0);
            acc[nt] = __builtin_amdgcn_mfma_f32_16x16x32_f16(al, bh, acc[nt], 0, 0, 0);
            acc[nt] = __builtin_amdgcn_mfma_f32_16x16x32_f16(ah, bl, acc[nt], 0, 0, 0);
        }
    }
    // C/D layout: col = lane&15, row = (lane>>4)*4 + reg
    #pragma unroll
    for (int nt = 0; nt < NT; ++nt) {
        int col = nt * 16 + m;
        float b = (col < COUT / 2) ? B0[col] : B1[col - COUT / 2];
        #pragma unroll
        for (int r = 0; r < 4; ++r) {
            long grow = row0 + q * 4 + r;
            out[(size_t)grow * COUT + col] = (_Float16)(acc[nt][r] + b);
        }
    }
}

// ---------------- conv1 edge phase (fp16 buf [N,256] = xl(128) | xr(128)) ----------------

__global__ __launch_bounds__(256) void logits1(const _Float16* __restrict__ buf,
                                               const int* __restrict__ adj,
                                               const int* __restrict__ adjd,
                                               const float* __restrict__ att,   // [128]
                                               float* __restrict__ w0, float* __restrict__ w1,
                                               int T) {
    int t = blockIdx.x * 256 + threadIdx.x;
    if (t >= T) return;
    int src = adj[t], dst = adjd[t];
    const half8* xl = (const half8*)&buf[(size_t)src * 256];
    const half8* xr = (const half8*)&buf[(size_t)dst * 256 + 128];
    float s0 = 0.f, s1 = 0.f;
    #pragma unroll
    for (int k = 0; k < 8; ++k) {
        half8 l = xl[k], r = xr[k];
        #pragma unroll
        for (int j = 0; j < 8; ++j)
            s0 += att[k * 8 + j] * lrelu((float)l[j] + (float)r[j], ATT_SLOPE);
    }
    #pragma unroll
    for (int k = 8; k < 16; ++k) {
        half8 l = xl[k], r = xr[k];
        #pragma unroll
        for (int j = 0; j < 8; ++j)
            s1 += att[k * 8 + j] * lrelu((float)l[j] + (float)r[j], ATT_SLOPE);
    }
    w0[t] = __expf(s0);
    w1[t] = __expf(s1);
}

// One wave per node, single pass; outputs h1 as hi/lo fp16 (input to gemm2).
__global__ __launch_bounds__(256) void agg1(const _Float16* __restrict__ buf,
                                            const int* __restrict__ rowptr,
                                            const int* __restrict__ adj,
                                            const float* __restrict__ w0,
                                            const float* __restrict__ w1,
                                            const float* __restrict__ bias,   // [128]
                                            _Float16* __restrict__ h1hi,
                                            _Float16* __restrict__ h1lo, int n) {
    int wid = threadIdx.x >> 6, lane = threadIdx.x & 63;
    int node = blockIdx.x * 4 + wid;
    if (node >= n) return;
    const int s = rowptr[node], e = rowptr[node + 1];
    const float* wsel = (lane < 32) ? w0 : w1;

    float2 a0 = {0.f, 0.f}, a1 = {0.f, 0.f}, a2 = {0.f, 0.f}, a3 = {0.f, 0.f};
    float d0 = 0.f, d1 = 0.f, d2 = 0.f, d3 = 0.f;
    int j = s;
    for (; j + 3 < e; j += 4) {
        int s0 = adj[j], s1 = adj[j + 1], s2 = adj[j + 2], s3 = adj[j + 3];
        float q0 = wsel[j], q1 = wsel[j + 1], q2 = wsel[j + 2], q3 = wsel[j + 3];
        half2v v0 = *(const half2v*)&buf[(size_t)s0 * 256 + lane * 2];
        half2v v1 = *(const half2v*)&buf[(size_t)s1 * 256 + lane * 2];
        half2v v2 = *(const half2v*)&buf[(size_t)s2 * 256 + lane * 2];
        half2v v3 = *(const half2v*)&buf[(size_t)s3 * 256 + lane * 2];
        a0.x += q0 * (float)v0[0]; a0.y += q0 * (float)v0[1]; d0 += q0;
        a1.x += q1 * (float)v1[0]; a1.y += q1 * (float)v1[1]; d1 += q1;
        a2.x += q2 * (float)v2[0]; a2.y += q2 * (float)v2[1]; d2 += q2;
        a3.x += q3 * (float)v3[0]; a3.y += q3 * (float)v3[1]; d3 += q3;
    }
    for (; j < e; ++j) {
        int s0 = adj[j];
        float q0 = wsel[j];
        half2v v0 = *(const half2v*)&buf[(size_t)s0 * 256 + lane * 2];
        a0.x += q0 * (float)v0[0]; a0.y += q0 * (float)v0[1]; d0 += q0;
    }
    float inv = 1.f / (d0 + d1 + d2 + d3);
    float2 b = *(const float2*)&bias[lane * 2];
    float ox = lrelu((a0.x + a1.x + a2.x + a3.x) * inv + b.x, ACT_SLOPE);
    float oy = lrelu((a0.y + a1.y + a2.y + a3.y) * inv + b.y, ACT_SLOPE);
    half2v hv, lv;
    hv[0] = (_Float16)ox; lv[0] = (_Float16)(ox - (float)hv[0]);
    hv[1] = (_Float16)oy; lv[1] = (_Float16)(oy - (float)hv[1]);
    *(half2v*)&h1hi[(size_t)node * 128 + lane * 2] = hv;
    *(half2v*)&h1lo[(size_t)node * 128 + lane * 2] = lv;
}

// ---------------- conv2 edge phase (fp16 buf [N,128] = xl(64) | xr(64)) ----------------

__global__ __launch_bounds__(256) void logits2(const _Float16* __restrict__ buf,
                                               const int* __restrict__ adj,
                                               const int* __restrict__ adjd,
                                               const float* __restrict__ att,   // [64]
                                               float* __restrict__ w0, int T) {
    int t = blockIdx.x * 256 + threadIdx.x;
    if (t >= T) return;
    int src = adj[t], dst = adjd[t];
    const half8* xl = (const half8*)&buf[(size_t)src * 128];
    const half8* xr = (const half8*)&buf[(size_t)dst * 128 + 64];
    float s0 = 0.f;
    #pragma unroll
    for (int k = 0; k < 8; ++k) {
        half8 l = xl[k], r = xr[k];
        #pragma unroll
        for (int j = 0; j < 8; ++j)
            s0 += att[k * 8 + j] * lrelu((float)l[j] + (float)r[j], ATT_SLOPE);
    }
    w0[t] = __expf(s0);
}

__global__ __launch_bounds__(256) void agg2(const _Float16* __restrict__ buf,
                                            const int* __restrict__ rowptr,
                                            const int* __restrict__ adj,
                                            const float* __restrict__ w0,
                                            const float* __restrict__ bias,  // [64]
                                            float* __restrict__ h2, int n) {
    int wid = threadIdx.x >> 6, lane = threadIdx.x & 63;
    int node = blockIdx.x * 4 + wid;
    if (node >= n) return;
    const int s = rowptr[node], e = rowptr[node + 1];

    float a0 = 0.f, a1 = 0.f, a2 = 0.f, a3 = 0.f;
    float d0 = 0.f, d1 = 0.f, d2 = 0.f, d3 = 0.f;
    int j = s;
    for (; j + 3 < e; j += 4) {
        int s0 = adj[j], s1 = adj[j + 1], s2 = adj[j + 2], s3 = adj[j + 3];
        float q0 = w0[j], q1 = w0[j + 1], q2 = w0[j + 2], q3 = w0[j + 3];
        float v0 = (float)buf[(size_t)s0 * 128 + lane];
        float v1 = (float)buf[(size_t)s1 * 128 + lane];
        float v2 = (float)buf[(size_t)s2 * 128 + lane];
        float v3 = (float)buf[(size_t)s3 * 128 + lane];
        a0 += q0 * v0; d0 += q0;
        a1 += q1 * v1; d1 += q1;
        a2 += q2 * v2; d2 += q2;
        a3 += q3 * v3; d3 += q3;
    }
    for (; j < e; ++j) {
        int s0 = adj[j];
        float q0 = w0[j];
        a0 += q0 * (float)buf[(size_t)s0 * 128 + lane];
        d0 += q0;
    }
    float acc = (a0 + a1 + a2 + a3) / (d0 + d1 + d2 + d3);
    h2[(size_t)node * 64 + lane] = lrelu(acc + bias[lane], ACT_SLOPE);
}

// ---------------- global mean pool (batch sorted) + fc1 + lrelu + fc2 ----------------

__device__ __forceinline__ int lower_bound(const int* a, int n, int v) {
    int lo = 0, hi = n;
    while (lo < hi) { int mid = (lo + hi) >> 1; if (a[mid] < v) lo = mid + 1; else hi = mid; }
    return lo;
}

__global__ __launch_bounds__(256) void pool_mlp(const float* __restrict__ h2,   // [N,64]
                                                const int* __restrict__ batch,  // [N] sorted
                                                const float* __restrict__ fc1_w,
                                                const float* __restrict__ fc1_b,
                                                const float* __restrict__ fc2_w,
                                                const float* __restrict__ fc2_b,
                                                float* __restrict__ out, int n) {
    const int g = blockIdx.x;
    const int tid = threadIdx.x;
    const int c = tid & 63, q = tid >> 6;
    __shared__ float partial[4][64];
    __shared__ float pooled[64];
    __shared__ float hmid[64];

    int lo = lower_bound(batch, n, g);
    int hi = lower_bound(batch, n, g + 1);

    float sum = 0.f;
    for (int i = lo + q; i < hi; i += 4) sum += h2[(size_t)i * 64 + c];
    partial[q][c] = sum;
    __syncthreads();
    if (q == 0) {
        float s = partial[0][c] + partial[1][c] + partial[2][c] + partial[3][c];
        int cnt = hi - lo;
        pooled[c] = s / (float)max(cnt, 1);
    }
    __syncthreads();
    if (tid < 64) {
        float acc = fc1_b[tid];
        const float* w = &fc1_w[(size_t)tid * 64];
        #pragma unroll
        for (int k = 0; k < 64; ++k) acc += pooled[k] * w[k];
        hmid[tid] = lrelu(acc, ACT_SLOPE);
    }
    __syncthreads();
    for (int o = tid; o < 768; o += 256) {
        float acc = fc2_b[o];
        const float* w = &fc2_w[(size_t)o * 64];
        #pragma unroll
        for (int k = 0; k < 64; ++k) acc += hmid[k] * w[k];
        out[(size_t)g * 768 + o] = acc;
    }
}

// ---------------- launch ----------------

extern "C" void kernel_launch(void* const* d_in, const int* in_sizes, int n_in,
                              void* d_out, int out_size, void* d_ws, size_t ws_size,
                              hipStream_t stream) {
    const float* x     = (const float*)d_in[0];
    const int*   ei    = (const int*)d_in[1];
    const int*   batch = (const int*)d_in[2];
    const float* w1_l  = (const float*)d_in[3];
    const float* b1_l  = (const float*)d_in[4];
    const float* w1_r  = (const float*)d_in[5];
    const float* b1_r  = (const float*)d_in[6];
    const float* att1  = (const float*)d_in[7];
    const float* bias1 = (const float*)d_in[8];
    const float* w2_l  = (const float*)d_in[9];
    const float* b2_l  = (const float*)d_in[10];
    const float* w2_r  = (const float*)d_in[11];
    const float* b2_r  = (const float*)d_in[12];
    const float* att2  = (const float*)d_in[13];
    const float* bias2 = (const float*)d_in[14];
    const float* fc1_w = (const float*)d_in[15];
    const float* fc1_b = (const float*)d_in[16];
    const float* fc2_w = (const float*)d_in[17];
    const float* fc2_b = (const float*)d_in[18];
    float* out = (float*)d_out;

    const int N = in_sizes[2];
    const int E = in_sizes[1] / 2;
    const int T = E + N;
    const int G = out_size / 768;

    char* ws = (char*)d_ws;
    size_t off = 0;
    auto alloc = [&](size_t bytes) -> void* {
        void* p = ws + off;
        off = (off + bytes + 255) & ~(size_t)255;
        return p;
    };
    int*      deg    = (int*)alloc((size_t)N * 4);
    int*      rowptr = (int*)alloc((size_t)(N + 1) * 4);
    int*      cursor = (int*)alloc((size_t)N * 4);
    int*      bsum   = (int*)alloc(1024);
    int*      boff   = (int*)alloc(1024);
    int*      adj    = (int*)alloc((size_t)T * 4);
    int*      adjd   = (int*)alloc((size_t)T * 4);
    float*    ew0    = (float*)alloc((size_t)T * 4);
    float*    ew1    = (float*)alloc((size_t)T * 4);
    _Float16* xhi    = (_Float16*)alloc((size_t)N * 128 * 2);
    _Float16* xlo    = (_Float16*)alloc((size_t)N * 128 * 2);
    _Float16* W1h    = (_Float16*)alloc(32768 * 2);
    _Float16* W1lo   = (_Float16*)alloc(32768 * 2);
    _Float16* W2h    = (_Float16*)alloc(16384 * 2);
    _Float16* W2lo   = (_Float16*)alloc(16384 * 2);
    _Float16* buf1   = (_Float16*)alloc((size_t)N * 256 * 2);   // fp16 now
    // lifetime aliasing: xhi/xlo dead after gemm1 -> reuse for h1 hi/lo;
    // buf1 (N*512 B) dead after agg1 -> first half buf2 (fp16 [N,128] = N*256 B),
    // second half h2 (fp32 [N,64] = N*256 B).
    _Float16* h1hi = xhi;
    _Float16* h1lo = xlo;
    _Float16* buf2 = buf1;
    float*    h2   = (float*)((char*)buf1 + (size_t)N * 256);

    const int nbN  = (N + 255) / 256;
    const int nbT  = (T + 255) / 256;
    const int mfmG = (N + 63) / 64;
    const int edgG = (N + 3) / 4;
    const int encG = ((N * 128 / 4) + 255) / 256;

    // ---- CSR build ----
    hipMemsetAsync(deg, 0, (size_t)N * 4, stream);
    k_count<<<nbT, 256, 0, stream>>>(ei, E, N, deg);
    k_scan_block<<<nbN, 256, 0, stream>>>(deg, N, rowptr + 1, bsum);
    k_scan_bsum<<<1, 256, 0, stream>>>(bsum, nbN, boff);
    k_scan_add<<<nbN, 256, 0, stream>>>(rowptr, boff, N);
    hipMemsetAsync(cursor, 0, (size_t)N * 4, stream);
    k_scatter<<<nbT, 256, 0, stream>>>(ei, E, N, rowptr, cursor, adj, adjd);

    // ---- encodes ----
    k_encode_w<<<192, 256, 0, stream>>>(w1_l, w1_r, w2_l, w2_r, W1h, W1lo, W2h, W2lo);
    k_encode4<<<encG, 256, 0, stream>>>(x, xhi, xlo, N * 128 / 4);

    // ---- conv1 ----
    gemm_mfma<256><<<mfmG, 256, 0, stream>>>(xhi, xlo, N, W1h, W1lo, b1_l, b1_r, buf1);
    logits1<<<nbT, 256, 0, stream>>>(buf1, adj, adjd, att1, ew0, ew1, T);
    agg1<<<edgG, 256, 0, stream>>>(buf1, rowptr, adj, ew0, ew1, bias1, h1hi, h1lo, N);

    // ---- conv2 ----
    gemm_mfma<128><<<mfmG, 256, 0, stream>>>(h1hi, h1lo, N, W2h, W2lo, b2_l, b2_r, buf2);
    logits2<<<nbT, 256, 0, stream>>>(buf2, adj, adjd, att2, ew0, T);
    agg2<<<edgG, 256, 0, stream>>>(buf2, rowptr, adj, ew0, bias2, h2, N);

    // ---- pool + MLP head ----
    pool_mlp<<<G, 256, 0, stream>>>(h2, batch, fc1_w, fc1_b, fc2_w, fc2_b, out, N);
}

// Round 6
// 359.117 us; speedup vs baseline: 2.0533x; 1.3779x over previous
//
#include <hip/hip_runtime.h>

#define ATT_SLOPE 0.2f
#define ACT_SLOPE 0.01f

typedef _Float16 half8  __attribute__((ext_vector_type(8)));
typedef _Float16 half2v __attribute__((ext_vector_type(2)));
typedef float    floatx4 __attribute__((ext_vector_type(4)));

__device__ __forceinline__ float lrelu(float v, float s) {
    return fmaxf(v, v * s);
}

// ---------------- CSR build (edges grouped by dst, self loops appended) ----------------

__global__ __launch_bounds__(256) void k_count(const int* __restrict__ ei, int E, int N,
                                               int* __restrict__ deg) {
    int i = blockIdx.x * 256 + threadIdx.x;
    int total = E + N;
    if (i >= total) return;
    int dst = (i < E) ? ei[E + i] : (i - E);
    atomicAdd(&deg[dst], 1);
}

__global__ __launch_bounds__(256) void k_scan_block(const int* __restrict__ deg, int n,
                                                    int* __restrict__ rp1, int* __restrict__ bsum) {
    __shared__ int s[256];
    int tid = threadIdx.x;
    int i = blockIdx.x * 256 + tid;
    s[tid] = (i < n) ? deg[i] : 0;
    __syncthreads();
    for (int off = 1; off < 256; off <<= 1) {
        int t = (tid >= off) ? s[tid - off] : 0;
        __syncthreads();
        s[tid] += t;
        __syncthreads();
    }
    if (i < n) rp1[i] = s[tid];
    if (tid == 255) bsum[blockIdx.x] = s[255];
}

__global__ __launch_bounds__(256) void k_scan_bsum(const int* __restrict__ bsum, int nb,
                                                   int* __restrict__ boff) {
    __shared__ int s[256];
    int tid = threadIdx.x;
    s[tid] = (tid < nb) ? bsum[tid] : 0;
    __syncthreads();
    for (int off = 1; off < 256; off <<= 1) {
        int t = (tid >= off) ? s[tid - off] : 0;
        __syncthreads();
        s[tid] += t;
        __syncthreads();
    }
    if (tid < nb) boff[tid] = (tid > 0) ? s[tid - 1] : 0;
}

__global__ __launch_bounds__(256) void k_scan_add(int* __restrict__ rowptr,
                                                  const int* __restrict__ boff, int n) {
    int i = blockIdx.x * 256 + threadIdx.x;
    if (i < n) rowptr[i + 1] += boff[blockIdx.x];
    if (i == 0) rowptr[0] = 0;
}

__global__ __launch_bounds__(256) void k_scatter(const int* __restrict__ ei, int E, int N,
                                                 const int* __restrict__ rowptr,
                                                 int* __restrict__ cursor,
                                                 int* __restrict__ adj) {
    int i = blockIdx.x * 256 + threadIdx.x;
    int total = E + N;
    if (i >= total) return;
    int src, dst;
    if (i < E) { src = ei[i]; dst = ei[E + i]; } else { src = i - E; dst = i - E; }
    int pos = atomicAdd(&cursor[dst], 1);
    adj[rowptr[dst] + pos] = src;
}

// ---------------- weight hi/lo fp16 split encode (all four matrices, one launch) ------------

__global__ __launch_bounds__(256) void k_encode_w(const float* __restrict__ w1l,
                                                  const float* __restrict__ w1r,
                                                  const float* __restrict__ w2l,
                                                  const float* __restrict__ w2r,
                                                  _Float16* __restrict__ W1h,
                                                  _Float16* __restrict__ W1lo,
                                                  _Float16* __restrict__ W2h,
                                                  _Float16* __restrict__ W2lo) {
    int i = blockIdx.x * 256 + threadIdx.x;   // 0 .. 49151
    if (i >= 49152) return;
    float v;
    _Float16 *ph, *pl;
    int idx;
    if (i < 32768) {
        idx = i;
        v = (i < 16384) ? w1l[i] : w1r[i - 16384];
        ph = W1h; pl = W1lo;
    } else {
        int j = i - 32768;
        idx = j;
        v = (j < 8192) ? w2l[j] : w2r[j - 8192];
        ph = W2h; pl = W2lo;
    }
    _Float16 h = (_Float16)v;
    ph[idx] = h;
    pl[idx] = (_Float16)(v - (float)h);
}

// ---------------- MFMA split-f16 dual linear, LDS-staged W, fp16 out ----------------
// 512 threads = 8 waves; wave computes a 16-row x COUT tile. W (hi+lo) staged into LDS in
// 4 K-phases of 32 (padded stride 40 halfs -> bandwidth-floor bank pattern).
// IN_F32: A is fp32, hi/lo split done in-register (gemm1); else A is pre-split hi/lo fp16.

template <int COUT, bool IN_F32>
__global__ __launch_bounds__(512) void gemm_mfma(const float* __restrict__ Af,
                                                 const _Float16* __restrict__ Ahi,
                                                 const _Float16* __restrict__ Alo, int n_rows,
                                                 const _Float16* __restrict__ Whi,
                                                 const _Float16* __restrict__ Wlo,
                                                 const float* __restrict__ B0,
                                                 const float* __restrict__ B1,
                                                 _Float16* __restrict__ out) {
    constexpr int NT = COUT / 16;
    constexpr int WS = 40;                      // 32 + 8 pad (16B-aligned, conflict-floor)
    __shared__ _Float16 sWh[COUT][WS];
    __shared__ _Float16 sWl[COUT][WS];
    const int tid = threadIdx.x;
    const int lane = tid & 63, wv = tid >> 6;
    const int m = lane & 15, q = lane >> 4;
    const long row0 = ((long)blockIdx.x * 8 + wv) * 16;
    const bool active = row0 < n_rows;          // wave-uniform (n_rows % 16 == 0)
    const long arow = row0 + m;

    floatx4 acc[NT] = {};
    for (int kk = 0; kk < 128; kk += 32) {
        __syncthreads();                        // protect previous phase's reads
        for (int t = tid; t < COUT * 4; t += 512) {
            int c = t >> 2, ch = t & 3;
            *(half8*)&sWh[c][ch * 8] = *(const half8*)&Whi[(size_t)c * 128 + kk + ch * 8];
            *(half8*)&sWl[c][ch * 8] = *(const half8*)&Wlo[(size_t)c * 128 + kk + ch * 8];
        }
        __syncthreads();
        if (active) {
            half8 ah, al;
            if constexpr (IN_F32) {
                float4 a0 = *(const float4*)&Af[(size_t)arow * 128 + kk + q * 8];
                float4 a1 = *(const float4*)&Af[(size_t)arow * 128 + kk + q * 8 + 4];
                float av[8] = {a0.x, a0.y, a0.z, a0.w, a1.x, a1.y, a1.z, a1.w};
                #pragma unroll
                for (int x = 0; x < 8; ++x) {
                    ah[x] = (_Float16)av[x];
                    al[x] = (_Float16)(av[x] - (float)ah[x]);
                }
            } else {
                ah = *(const half8*)&Ahi[(size_t)arow * 128 + kk + q * 8];
                al = *(const half8*)&Alo[(size_t)arow * 128 + kk + q * 8];
            }
            #pragma unroll
            for (int nt = 0; nt < NT; ++nt) {
                half8 bh = *(const half8*)&sWh[nt * 16 + m][q * 8];
                half8 bl = *(const half8*)&sWl[nt * 16 + m][q * 8];
                acc[nt] = __builtin_amdgcn_mfma_f32_16x16x32_f16(ah, bh, acc[nt], 0, 0, 0);
                acc[nt] = __builtin_amdgcn_mfma_f32_16x16x32_f16(al, bh, acc[nt], 0, 0, 0);
                acc[nt] = __builtin_amdgcn_mfma_f32_16x16x32_f16(ah, bl, acc[nt], 0, 0, 0);
            }
        }
    }
    if (active) {
        // C/D layout: col = lane&15, row = (lane>>4)*4 + reg
        #pragma unroll
        for (int nt = 0; nt < NT; ++nt) {
            int col = nt * 16 + m;
            float b = (col < COUT / 2) ? B0[col] : B1[col - COUT / 2];
            #pragma unroll
            for (int r = 0; r < 4; ++r) {
                long grow = row0 + q * 4 + r;
                out[(size_t)grow * COUT + col] = (_Float16)(acc[nt][r] + b);
            }
        }
    }
}

// ---------------- fused GATv2 conv1 edge phase (heads=2, ch=64) ----------------
// buf fp16 [N,256] = xl(128)|xr(128). Wave per node; chunks of <=32 edges.
// Phase A: lane pair (j, j+32) gathers xl[src_j] (each half of 128 ch) ONCE, parks it in
// LDS, and computes the per-head logit (grp0 -> head0 ch0-63, grp1 -> head1 ch64-127).
// Phase B: channel-parallel (lane -> 2 ch) unnormalized aggregate from LDS.

__global__ __launch_bounds__(256) void conv1_fused(const _Float16* __restrict__ buf,
                                                   const int* __restrict__ rowptr,
                                                   const int* __restrict__ adj,
                                                   const float* __restrict__ att,   // [128]
                                                   const float* __restrict__ bias,  // [128]
                                                   _Float16* __restrict__ h1hi,
                                                   _Float16* __restrict__ h1lo, int n) {
    __shared__ _Float16 sxl[4][32][136];   // 272B row stride: 16B-aligned, b128 at BW floor
    __shared__ _Float16 sxr[4][128];
    __shared__ float    sw[4][2][32];
    __shared__ float    satt[128];
    const int tid = threadIdx.x, lane = tid & 63, wv = tid >> 6;
    if (tid < 128) satt[tid] = att[tid];
    __syncthreads();                        // all threads reach; no barriers after this
    int node = blockIdx.x * 4 + wv;
    if (node >= n) return;

    const int jlane = lane & 31;
    const int grp = lane >> 5;             // 0: ch 0-63 / head0, 1: ch 64-127 / head1
    const int chbase = grp * 64;
    if (lane < 16)
        *(half8*)&sxr[wv][lane * 8] = *(const half8*)&buf[(size_t)node * 256 + 128 + lane * 8];
    asm volatile("s_waitcnt lgkmcnt(0)" ::: "memory");

    const int s = rowptr[node], e = rowptr[node + 1];
    float2 acc = {0.f, 0.f};
    float den = 0.f;
    for (int c0 = s; c0 < e; c0 += 32) {
        const int cnt = min(32, e - c0);
        if (jlane < cnt) {
            int src = adj[c0 + jlane];
            const _Float16* xlp = &buf[(size_t)src * 256 + chbase];
            float sacc = 0.f;
            #pragma unroll
            for (int k = 0; k < 8; ++k) {
                half8 l = *(const half8*)&xlp[k * 8];
                half8 r = *(const half8*)&sxr[wv][chbase + k * 8];
                *(half8*)&sxl[wv][jlane][chbase + k * 8] = l;
                float4 a0 = *(const float4*)&satt[chbase + k * 8];
                float4 a1 = *(const float4*)&satt[chbase + k * 8 + 4];
                float m0 = (float)l[0] + (float)r[0];
                float m1 = (float)l[1] + (float)r[1];
                float m2 = (float)l[2] + (float)r[2];
                float m3 = (float)l[3] + (float)r[3];
                float m4 = (float)l[4] + (float)r[4];
                float m5 = (float)l[5] + (float)r[5];
                float m6 = (float)l[6] + (float)r[6];
                float m7 = (float)l[7] + (float)r[7];
                sacc += a0.x * lrelu(m0, ATT_SLOPE) + a0.y * lrelu(m1, ATT_SLOPE)
                      + a0.z * lrelu(m2, ATT_SLOPE) + a0.w * lrelu(m3, ATT_SLOPE)
                      + a1.x * lrelu(m4, ATT_SLOPE) + a1.y * lrelu(m5, ATT_SLOPE)
                      + a1.z * lrelu(m6, ATT_SLOPE) + a1.w * lrelu(m7, ATT_SLOPE);
            }
            sw[wv][grp][jlane] = __expf(sacc);
        }
        asm volatile("s_waitcnt lgkmcnt(0)" ::: "memory");
        // phase B: lane -> channels (2*lane, 2*lane+1); its head's weights
        for (int j = 0; j < cnt; ++j) {
            float w = sw[wv][grp][j];
            half2v v = *(const half2v*)&sxl[wv][j][lane * 2];
            acc.x += w * (float)v[0];
            acc.y += w * (float)v[1];
            den += w;
        }
        asm volatile("s_waitcnt lgkmcnt(0)" ::: "memory");  // drain reads before next overwrite
    }
    float inv = 1.f / den;
    float2 b = *(const float2*)&bias[lane * 2];
    float ox = lrelu(acc.x * inv + b.x, ACT_SLOPE);
    float oy = lrelu(acc.y * inv + b.y, ACT_SLOPE);
    half2v hv, lv;
    hv[0] = (_Float16)ox; lv[0] = (_Float16)(ox - (float)hv[0]);
    hv[1] = (_Float16)oy; lv[1] = (_Float16)(oy - (float)hv[1]);
    *(half2v*)&h1hi[(size_t)node * 128 + lane * 2] = hv;
    *(half2v*)&h1lo[(size_t)node * 128 + lane * 2] = lv;
}

// ---------------- fused GATv2 conv2 edge phase (heads=1, ch=64) ----------------
// buf fp16 [N,128] = xl(64)|xr(64). Lane pair (j, j+32) each does 32 ch; logit combined
// via shfl_xor(32). Phase B: lane -> 1 channel.

__global__ __launch_bounds__(256) void conv2_fused(const _Float16* __restrict__ buf,
                                                   const int* __restrict__ rowptr,
                                                   const int* __restrict__ adj,
                                                   const float* __restrict__ att,   // [64]
                                                   const float* __restrict__ bias,  // [64]
                                                   float* __restrict__ h2, int n) {
    __shared__ _Float16 sxl[4][32][72];
    __shared__ _Float16 sxr[4][64];
    __shared__ float    sw[4][32];
    __shared__ float    satt[64];
    const int tid = threadIdx.x, lane = tid & 63, wv = tid >> 6;
    if (tid < 64) satt[tid] = att[tid];
    __syncthreads();
    int node = blockIdx.x * 4 + wv;
    if (node >= n) return;

    const int jlane = lane & 31;
    const int grp = lane >> 5;             // 0: ch 0-31, 1: ch 32-63
    const int chbase = grp * 32;
    if (lane < 8)
        *(half8*)&sxr[wv][lane * 8] = *(const half8*)&buf[(size_t)node * 128 + 64 + lane * 8];
    asm volatile("s_waitcnt lgkmcnt(0)" ::: "memory");

    const int s = rowptr[node], e = rowptr[node + 1];
    float acc = 0.f, den = 0.f;
    for (int c0 = s; c0 < e; c0 += 32) {
        const int cnt = min(32, e - c0);
        float sacc = 0.f;
        if (jlane < cnt) {
            int src = adj[c0 + jlane];
            const _Float16* xlp = &buf[(size_t)src * 128 + chbase];
            #pragma unroll
            for (int k = 0; k < 4; ++k) {
                half8 l = *(const half8*)&xlp[k * 8];
                half8 r = *(const half8*)&sxr[wv][chbase + k * 8];
                *(half8*)&sxl[wv][jlane][chbase + k * 8] = l;
                float4 a0 = *(const float4*)&satt[chbase + k * 8];
                float4 a1 = *(const float4*)&satt[chbase + k * 8 + 4];
                float m0 = (float)l[0] + (float)r[0];
                float m1 = (float)l[1] + (float)r[1];
                float m2 = (float)l[2] + (float)r[2];
                float m3 = (float)l[3] + (float)r[3];
                float m4 = (float)l[4] + (float)r[4];
                float m5 = (float)l[5] + (float)r[5];
                float m6 = (float)l[6] + (float)r[6];
                float m7 = (float)l[7] + (float)r[7];
                sacc += a0.x * lrelu(m0, ATT_SLOPE) + a0.y * lrelu(m1, ATT_SLOPE)
                      + a0.z * lrelu(m2, ATT_SLOPE) + a0.w * lrelu(m3, ATT_SLOPE)
                      + a1.x * lrelu(m4, ATT_SLOPE) + a1.y * lrelu(m5, ATT_SLOPE)
                      + a1.z * lrelu(m6, ATT_SLOPE) + a1.w * lrelu(m7, ATT_SLOPE);
            }
        }
        float efull = sacc + __shfl_xor(sacc, 32);   // combine the two half-logits
        if (grp == 0 && jlane < cnt) sw[wv][jlane] = __expf(efull);
        asm volatile("s_waitcnt lgkmcnt(0)" ::: "memory");
        for (int j = 0; j < cnt; ++j) {
            float w = sw[wv][j];
            float v = (float)sxl[wv][j][lane];
            acc += w * v;
            den += w;
        }
        asm volatile("s_waitcnt lgkmcnt(0)" ::: "memory");
    }
    h2[(size_t)node * 64 + lane] = lrelu(acc / den + bias[lane], ACT_SLOPE);
}

// ---------------- global mean pool (batch sorted) + fc1 + lrelu + fc2 ----------------

__device__ __forceinline__ int lower_bound(const int* a, int n, int v) {
    int lo = 0, hi = n;
    while (lo < hi) { int mid = (lo + hi) >> 1; if (a[mid] < v) lo = mid + 1; else hi = mid; }
    return lo;
}

__global__ __launch_bounds__(256) void pool_mlp(const float* __restrict__ h2,   // [N,64]
                                                const int* __restrict__ batch,  // [N] sorted
                                                const float* __restrict__ fc1_w,
                                                const float* __restrict__ fc1_b,
                                                const float* __restrict__ fc2_w,
                                                const float* __restrict__ fc2_b,
                                                float* __restrict__ out, int n) {
    const int g = blockIdx.x;
    const int tid = threadIdx.x;
    const int c = tid & 63, q = tid >> 6;
    __shared__ float partial[4][64];
    __shared__ float pooled[64];
    __shared__ float hmid[64];

    int lo = lower_bound(batch, n, g);
    int hi = lower_bound(batch, n, g + 1);

    float sum = 0.f;
    for (int i = lo + q; i < hi; i += 4) sum += h2[(size_t)i * 64 + c];
    partial[q][c] = sum;
    __syncthreads();
    if (q == 0) {
        float s = partial[0][c] + partial[1][c] + partial[2][c] + partial[3][c];
        int cnt = hi - lo;
        pooled[c] = s / (float)max(cnt, 1);
    }
    __syncthreads();
    if (tid < 64) {
        float acc = fc1_b[tid];
        const float* w = &fc1_w[(size_t)tid * 64];
        #pragma unroll
        for (int k = 0; k < 64; ++k) acc += pooled[k] * w[k];
        hmid[tid] = lrelu(acc, ACT_SLOPE);
    }
    __syncthreads();
    for (int o = tid; o < 768; o += 256) {
        float acc = fc2_b[o];
        const float* w = &fc2_w[(size_t)o * 64];
        #pragma unroll
        for (int k = 0; k < 64; ++k) acc += hmid[k] * w[k];
        out[(size_t)g * 768 + o] = acc;
    }
}

// ---------------- launch ----------------

extern "C" void kernel_launch(void* const* d_in, const int* in_sizes, int n_in,
                              void* d_out, int out_size, void* d_ws, size_t ws_size,
                              hipStream_t stream) {
    const float* x     = (const float*)d_in[0];
    const int*   ei    = (const int*)d_in[1];
    const int*   batch = (const int*)d_in[2];
    const float* w1_l  = (const float*)d_in[3];
    const float* b1_l  = (const float*)d_in[4];
    const float* w1_r  = (const float*)d_in[5];
    const float* b1_r  = (const float*)d_in[6];
    const float* att1  = (const float*)d_in[7];
    const float* bias1 = (const float*)d_in[8];
    const float* w2_l  = (const float*)d_in[9];
    const float* b2_l  = (const float*)d_in[10];
    const float* w2_r  = (const float*)d_in[11];
    const float* b2_r  = (const float*)d_in[12];
    const float* att2  = (const float*)d_in[13];
    const float* bias2 = (const float*)d_in[14];
    const float* fc1_w = (const float*)d_in[15];
    const float* fc1_b = (const float*)d_in[16];
    const float* fc2_w = (const float*)d_in[17];
    const float* fc2_b = (const float*)d_in[18];
    float* out = (float*)d_out;

    const int N = in_sizes[2];
    const int E = in_sizes[1] / 2;
    const int T = E + N;
    const int G = out_size / 768;

    char* ws = (char*)d_ws;
    size_t off = 0;
    auto alloc = [&](size_t bytes) -> void* {
        void* p = ws + off;
        off = (off + bytes + 255) & ~(size_t)255;
        return p;
    };
    int*      deg    = (int*)alloc((size_t)N * 4);
    int*      rowptr = (int*)alloc((size_t)(N + 1) * 4);
    int*      cursor = (int*)alloc((size_t)N * 4);
    int*      bsum   = (int*)alloc(1024);
    int*      boff   = (int*)alloc(1024);
    int*      adj    = (int*)alloc((size_t)T * 4);
    _Float16* h1hi   = (_Float16*)alloc((size_t)N * 128 * 2);
    _Float16* h1lo   = (_Float16*)alloc((size_t)N * 128 * 2);
    _Float16* W1h    = (_Float16*)alloc(32768 * 2);
    _Float16* W1lo   = (_Float16*)alloc(32768 * 2);
    _Float16* W2h    = (_Float16*)alloc(16384 * 2);
    _Float16* W2lo   = (_Float16*)alloc(16384 * 2);
    _Float16* buf1   = (_Float16*)alloc((size_t)N * 256 * 2);
    // lifetime aliasing: buf1 (N*512 B) dead after conv1_fused -> buf2 fp16 [N,128] (N*256 B)
    // in the first half, h2 fp32 [N,64] (N*256 B) in the second half.
    _Float16* buf2 = buf1;
    float*    h2   = (float*)((char*)buf1 + (size_t)N * 256);

    const int nbN  = (N + 255) / 256;
    const int nbT  = (T + 255) / 256;
    const int mfmG = (N / 16 + 7) / 8;          // 16-row tiles, 8 per block
    const int edgG = (N + 3) / 4;

    // ---- CSR build ----
    hipMemsetAsync(deg, 0, (size_t)N * 4, stream);
    k_count<<<nbT, 256, 0, stream>>>(ei, E, N, deg);
    k_scan_block<<<nbN, 256, 0, stream>>>(deg, N, rowptr + 1, bsum);
    k_scan_bsum<<<1, 256, 0, stream>>>(bsum, nbN, boff);
    k_scan_add<<<nbN, 256, 0, stream>>>(rowptr, boff, N);
    hipMemsetAsync(cursor, 0, (size_t)N * 4, stream);
    k_scatter<<<nbT, 256, 0, stream>>>(ei, E, N, rowptr, cursor, adj);

    // ---- weight encode ----
    k_encode_w<<<192, 256, 0, stream>>>(w1_l, w1_r, w2_l, w2_r, W1h, W1lo, W2h, W2lo);

    // ---- conv1 ----
    gemm_mfma<256, true><<<mfmG, 512, 0, stream>>>(x, nullptr, nullptr, N,
                                                   W1h, W1lo, b1_l, b1_r, buf1);
    conv1_fused<<<edgG, 256, 0, stream>>>(buf1, rowptr, adj, att1, bias1, h1hi, h1lo, N);

    // ---- conv2 ----
    gemm_mfma<128, false><<<mfmG, 512, 0, stream>>>(nullptr, h1hi, h1lo, N,
                                                    W2h, W2lo, b2_l, b2_r, buf2);
    conv2_fused<<<edgG, 256, 0, stream>>>(buf2, rowptr, adj, att2, bias2, h2, N);

    // ---- pool + MLP head ----
    pool_mlp<<<G, 256, 0, stream>>>(h2, batch, fc1_w, fc1_b, fc2_w, fc2_b, out, N);
}

// Round 7
// 353.493 us; speedup vs baseline: 2.0859x; 1.0159x over previous
//
#include <hip/hip_runtime.h>

#define ATT_SLOPE 0.2f
#define ACT_SLOPE 0.01f

typedef _Float16 half8  __attribute__((ext_vector_type(8)));
typedef _Float16 half2v __attribute__((ext_vector_type(2)));
typedef float    floatx4 __attribute__((ext_vector_type(4)));

#if defined(__has_builtin)
#if __has_builtin(__builtin_amdgcn_fdot2)
#define HAVE_FDOT2 1
#endif
#endif

__device__ __forceinline__ float lrelu(float v, float s) {
    return fmaxf(v, v * s);
}

// packed fp16 leaky-relu: max(v, 0.2*v) elementwise on a half2
__device__ __forceinline__ half2v lrelu2(half2v m) {
    half2v t = m * (_Float16)ATT_SLOPE;
    return __builtin_elementwise_max(m, t);
}

// dot of 2 fp16 pairs with fp32 accumulate
__device__ __forceinline__ float dot2(half2v a, half2v b, float c) {
#ifdef HAVE_FDOT2
    return __builtin_amdgcn_fdot2(a, b, c, false);
#else
    return c + (float)a[0] * (float)b[0] + (float)a[1] * (float)b[1];
#endif
}

// ---------------- CSR build (edges grouped by dst, self loops appended) ----------------

__global__ __launch_bounds__(256) void k_count(const int* __restrict__ ei, int E, int N,
                                               int* __restrict__ deg) {
    int i = blockIdx.x * 256 + threadIdx.x;
    int total = E + N;
    if (i >= total) return;
    int dst = (i < E) ? ei[E + i] : (i - E);
    atomicAdd(&deg[dst], 1);
}

__global__ __launch_bounds__(256) void k_scan_block(const int* __restrict__ deg, int n,
                                                    int* __restrict__ rp1, int* __restrict__ bsum) {
    __shared__ int s[256];
    int tid = threadIdx.x;
    int i = blockIdx.x * 256 + tid;
    s[tid] = (i < n) ? deg[i] : 0;
    __syncthreads();
    for (int off = 1; off < 256; off <<= 1) {
        int t = (tid >= off) ? s[tid - off] : 0;
        __syncthreads();
        s[tid] += t;
        __syncthreads();
    }
    if (i < n) rp1[i] = s[tid];
    if (tid == 255) bsum[blockIdx.x] = s[255];
}

__global__ __launch_bounds__(256) void k_scan_bsum(const int* __restrict__ bsum, int nb,
                                                   int* __restrict__ boff) {
    __shared__ int s[256];
    int tid = threadIdx.x;
    s[tid] = (tid < nb) ? bsum[tid] : 0;
    __syncthreads();
    for (int off = 1; off < 256; off <<= 1) {
        int t = (tid >= off) ? s[tid - off] : 0;
        __syncthreads();
        s[tid] += t;
        __syncthreads();
    }
    if (tid < nb) boff[tid] = (tid > 0) ? s[tid - 1] : 0;
}

__global__ __launch_bounds__(256) void k_scan_add(int* __restrict__ rowptr,
                                                  const int* __restrict__ boff, int n) {
    int i = blockIdx.x * 256 + threadIdx.x;
    if (i < n) rowptr[i + 1] += boff[blockIdx.x];
    if (i == 0) rowptr[0] = 0;
}

__global__ __launch_bounds__(256) void k_scatter(const int* __restrict__ ei, int E, int N,
                                                 const int* __restrict__ rowptr,
                                                 int* __restrict__ cursor,
                                                 int* __restrict__ adj) {
    int i = blockIdx.x * 256 + threadIdx.x;
    int total = E + N;
    if (i >= total) return;
    int src, dst;
    if (i < E) { src = ei[i]; dst = ei[E + i]; } else { src = i - E; dst = i - E; }
    int pos = atomicAdd(&cursor[dst], 1);
    adj[rowptr[dst] + pos] = src;
}

// ---------------- weight hi/lo fp16 split encode (all four matrices, one launch) ------------

__global__ __launch_bounds__(256) void k_encode_w(const float* __restrict__ w1l,
                                                  const float* __restrict__ w1r,
                                                  const float* __restrict__ w2l,
                                                  const float* __restrict__ w2r,
                                                  _Float16* __restrict__ W1h,
                                                  _Float16* __restrict__ W1lo,
                                                  _Float16* __restrict__ W2h,
                                                  _Float16* __restrict__ W2lo) {
    int i = blockIdx.x * 256 + threadIdx.x;   // 0 .. 49151
    if (i >= 49152) return;
    float v;
    _Float16 *ph, *pl;
    int idx;
    if (i < 32768) {
        idx = i;
        v = (i < 16384) ? w1l[i] : w1r[i - 16384];
        ph = W1h; pl = W1lo;
    } else {
        int j = i - 32768;
        idx = j;
        v = (j < 8192) ? w2l[j] : w2r[j - 8192];
        ph = W2h; pl = W2lo;
    }
    _Float16 h = (_Float16)v;
    ph[idx] = h;
    pl[idx] = (_Float16)(v - (float)h);
}

// ---------------- MFMA split-f16 dual linear, LDS-staged W, fp16 out ----------------

template <int COUT, bool IN_F32>
__global__ __launch_bounds__(512) void gemm_mfma(const float* __restrict__ Af,
                                                 const _Float16* __restrict__ Ahi,
                                                 const _Float16* __restrict__ Alo, int n_rows,
                                                 const _Float16* __restrict__ Whi,
                                                 const _Float16* __restrict__ Wlo,
                                                 const float* __restrict__ B0,
                                                 const float* __restrict__ B1,
                                                 _Float16* __restrict__ out) {
    constexpr int NT = COUT / 16;
    constexpr int WS = 40;                      // 32 + 8 pad (16B-aligned, conflict-floor)
    __shared__ _Float16 sWh[COUT][WS];
    __shared__ _Float16 sWl[COUT][WS];
    const int tid = threadIdx.x;
    const int lane = tid & 63, wv = tid >> 6;
    const int m = lane & 15, q = lane >> 4;
    const long row0 = ((long)blockIdx.x * 8 + wv) * 16;
    const bool active = row0 < n_rows;          // wave-uniform (n_rows % 16 == 0)
    const long arow = row0 + m;

    floatx4 acc[NT] = {};
    for (int kk = 0; kk < 128; kk += 32) {
        __syncthreads();                        // protect previous phase's reads
        for (int t = tid; t < COUT * 4; t += 512) {
            int c = t >> 2, ch = t & 3;
            *(half8*)&sWh[c][ch * 8] = *(const half8*)&Whi[(size_t)c * 128 + kk + ch * 8];
            *(half8*)&sWl[c][ch * 8] = *(const half8*)&Wlo[(size_t)c * 128 + kk + ch * 8];
        }
        __syncthreads();
        if (active) {
            half8 ah, al;
            if constexpr (IN_F32) {
                float4 a0 = *(const float4*)&Af[(size_t)arow * 128 + kk + q * 8];
                float4 a1 = *(const float4*)&Af[(size_t)arow * 128 + kk + q * 8 + 4];
                float av[8] = {a0.x, a0.y, a0.z, a0.w, a1.x, a1.y, a1.z, a1.w};
                #pragma unroll
                for (int x = 0; x < 8; ++x) {
                    ah[x] = (_Float16)av[x];
                    al[x] = (_Float16)(av[x] - (float)ah[x]);
                }
            } else {
                ah = *(const half8*)&Ahi[(size_t)arow * 128 + kk + q * 8];
                al = *(const half8*)&Alo[(size_t)arow * 128 + kk + q * 8];
            }
            #pragma unroll
            for (int nt = 0; nt < NT; ++nt) {
                half8 bh = *(const half8*)&sWh[nt * 16 + m][q * 8];
                half8 bl = *(const half8*)&sWl[nt * 16 + m][q * 8];
                acc[nt] = __builtin_amdgcn_mfma_f32_16x16x32_f16(ah, bh, acc[nt], 0, 0, 0);
                acc[nt] = __builtin_amdgcn_mfma_f32_16x16x32_f16(al, bh, acc[nt], 0, 0, 0);
                acc[nt] = __builtin_amdgcn_mfma_f32_16x16x32_f16(ah, bl, acc[nt], 0, 0, 0);
            }
        }
    }
    if (active) {
        // C/D layout: col = lane&15, row = (lane>>4)*4 + reg
        #pragma unroll
        for (int nt = 0; nt < NT; ++nt) {
            int col = nt * 16 + m;
            float b = (col < COUT / 2) ? B0[col] : B1[col - COUT / 2];
            #pragma unroll
            for (int r = 0; r < 4; ++r) {
                long grow = row0 + q * 4 + r;
                out[(size_t)grow * COUT + col] = (_Float16)(acc[nt][r] + b);
            }
        }
    }
}

// ---------------- fused GATv2 conv1 edge phase (heads=2, ch=64) ----------------
// Packed-fp16 logit path: pk_add + pk_mul + pk_max + v_dot2_f32_f16 = ~2 VALU ops/channel.

__global__ __launch_bounds__(256) void conv1_fused(const _Float16* __restrict__ buf,
                                                   const int* __restrict__ rowptr,
                                                   const int* __restrict__ adj,
                                                   const float* __restrict__ att,   // [128]
                                                   const float* __restrict__ bias,  // [128]
                                                   _Float16* __restrict__ h1hi,
                                                   _Float16* __restrict__ h1lo, int n) {
    __shared__ _Float16 sxl[4][32][136];   // 272B row stride: 16B-aligned
    __shared__ _Float16 sxr[4][128];
    __shared__ float    sw[4][2][32];
    __shared__ _Float16 satt[128];
    const int tid = threadIdx.x, lane = tid & 63, wv = tid >> 6;
    if (tid < 128) satt[tid] = (_Float16)att[tid];
    __syncthreads();                        // all threads reach; no block barriers after this
    int node = blockIdx.x * 4 + wv;
    if (node >= n) return;

    const int jlane = lane & 31;
    const int grp = lane >> 5;             // 0: ch 0-63 / head0, 1: ch 64-127 / head1
    const int chbase = grp * 64;
    if (lane < 16)
        *(half8*)&sxr[wv][lane * 8] = *(const half8*)&buf[(size_t)node * 256 + 128 + lane * 8];
    asm volatile("s_waitcnt lgkmcnt(0)" ::: "memory");

    const int s = rowptr[node], e = rowptr[node + 1];
    float2 acc = {0.f, 0.f};
    float den = 0.f;
    for (int c0 = s; c0 < e; c0 += 32) {
        const int cnt = min(32, e - c0);
        if (jlane < cnt) {
            int src = adj[c0 + jlane];
            const _Float16* xlp = &buf[(size_t)src * 256 + chbase];
            float sacc = 0.f;
            #pragma unroll
            for (int k = 0; k < 8; ++k) {
                half8 l = *(const half8*)&xlp[k * 8];
                half8 r = *(const half8*)&sxr[wv][chbase + k * 8];
                half8 a = *(const half8*)&satt[chbase + k * 8];
                *(half8*)&sxl[wv][jlane][chbase + k * 8] = l;
                #pragma unroll
                for (int p = 0; p < 4; ++p) {
                    half2v lp = {l[2 * p], l[2 * p + 1]};
                    half2v rp = {r[2 * p], r[2 * p + 1]};
                    half2v ap = {a[2 * p], a[2 * p + 1]};
                    sacc = dot2(lrelu2(lp + rp), ap, sacc);
                }
                #pragma unroll
                for (int p = 4; p < 8; ++p) {
                    half2v lp = {l[2 * p], l[2 * p + 1]};
                    half2v rp = {r[2 * p], r[2 * p + 1]};
                    half2v ap = {a[2 * p], a[2 * p + 1]};
                    sacc = dot2(lrelu2(lp + rp), ap, sacc);
                }
            }
            sw[wv][grp][jlane] = __expf(sacc);
        }
        asm volatile("s_waitcnt lgkmcnt(0)" ::: "memory");
        // phase B: lane -> channels (2*lane, 2*lane+1); its head's weights
        for (int j = 0; j < cnt; ++j) {
            float w = sw[wv][grp][j];
            half2v v = *(const half2v*)&sxl[wv][j][lane * 2];
            acc.x += w * (float)v[0];      // v_fma_mix_f32
            acc.y += w * (float)v[1];
            den += w;
        }
        asm volatile("s_waitcnt lgkmcnt(0)" ::: "memory");  // drain reads before next overwrite
    }
    float inv = 1.f / den;
    float2 b = *(const float2*)&bias[lane * 2];
    float ox = lrelu(acc.x * inv + b.x, ACT_SLOPE);
    float oy = lrelu(acc.y * inv + b.y, ACT_SLOPE);
    half2v hv, lv;
    hv[0] = (_Float16)ox; lv[0] = (_Float16)(ox - (float)hv[0]);
    hv[1] = (_Float16)oy; lv[1] = (_Float16)(oy - (float)hv[1]);
    *(half2v*)&h1hi[(size_t)node * 128 + lane * 2] = hv;
    *(half2v*)&h1lo[(size_t)node * 128 + lane * 2] = lv;
}

// ---------------- fused GATv2 conv2 edge phase (heads=1, ch=64) ----------------

__global__ __launch_bounds__(256) void conv2_fused(const _Float16* __restrict__ buf,
                                                   const int* __restrict__ rowptr,
                                                   const int* __restrict__ adj,
                                                   const float* __restrict__ att,   // [64]
                                                   const float* __restrict__ bias,  // [64]
                                                   float* __restrict__ h2, int n) {
    __shared__ _Float16 sxl[4][32][72];
    __shared__ _Float16 sxr[4][64];
    __shared__ float    sw[4][32];
    __shared__ _Float16 satt[64];
    const int tid = threadIdx.x, lane = tid & 63, wv = tid >> 6;
    if (tid < 64) satt[tid] = (_Float16)att[tid];
    __syncthreads();
    int node = blockIdx.x * 4 + wv;
    if (node >= n) return;

    const int jlane = lane & 31;
    const int grp = lane >> 5;             // 0: ch 0-31, 1: ch 32-63
    const int chbase = grp * 32;
    if (lane < 8)
        *(half8*)&sxr[wv][lane * 8] = *(const half8*)&buf[(size_t)node * 128 + 64 + lane * 8];
    asm volatile("s_waitcnt lgkmcnt(0)" ::: "memory");

    const int s = rowptr[node], e = rowptr[node + 1];
    float acc = 0.f, den = 0.f;
    for (int c0 = s; c0 < e; c0 += 32) {
        const int cnt = min(32, e - c0);
        float sacc = 0.f;
        if (jlane < cnt) {
            int src = adj[c0 + jlane];
            const _Float16* xlp = &buf[(size_t)src * 128 + chbase];
            #pragma unroll
            for (int k = 0; k < 4; ++k) {
                half8 l = *(const half8*)&xlp[k * 8];
                half8 r = *(const half8*)&sxr[wv][chbase + k * 8];
                half8 a = *(const half8*)&satt[chbase + k * 8];
                *(half8*)&sxl[wv][jlane][chbase + k * 8] = l;
                #pragma unroll
                for (int p = 0; p < 4; ++p) {
                    half2v lp = {l[2 * p], l[2 * p + 1]};
                    half2v rp = {r[2 * p], r[2 * p + 1]};
                    half2v ap = {a[2 * p], a[2 * p + 1]};
                    sacc = dot2(lrelu2(lp + rp), ap, sacc);
                }
            }
        }
        float efull = sacc + __shfl_xor(sacc, 32);   // combine the two half-logits
        if (grp == 0 && jlane < cnt) sw[wv][jlane] = __expf(efull);
        asm volatile("s_waitcnt lgkmcnt(0)" ::: "memory");
        for (int j = 0; j < cnt; ++j) {
            float w = sw[wv][j];
            acc += w * (float)sxl[wv][j][lane];       // v_fma_mix_f32
            den += w;
        }
        asm volatile("s_waitcnt lgkmcnt(0)" ::: "memory");
    }
    h2[(size_t)node * 64 + lane] = lrelu(acc / den + bias[lane], ACT_SLOPE);
}

// ---------------- global mean pool (batch sorted) + fc1 + lrelu + fc2 ----------------

__device__ __forceinline__ int lower_bound(const int* a, int n, int v) {
    int lo = 0, hi = n;
    while (lo < hi) { int mid = (lo + hi) >> 1; if (a[mid] < v) lo = mid + 1; else hi = mid; }
    return lo;
}

__global__ __launch_bounds__(256) void pool_mlp(const float* __restrict__ h2,   // [N,64]
                                                const int* __restrict__ batch,  // [N] sorted
                                                const float* __restrict__ fc1_w,
                                                const float* __restrict__ fc1_b,
                                                const float* __restrict__ fc2_w,
                                                const float* __restrict__ fc2_b,
                                                float* __restrict__ out, int n) {
    const int g = blockIdx.x;
    const int tid = threadIdx.x;
    const int c = tid & 63, q = tid >> 6;
    __shared__ float partial[4][64];
    __shared__ float pooled[64];
    __shared__ float hmid[64];

    int lo = lower_bound(batch, n, g);
    int hi = lower_bound(batch, n, g + 1);

    float sum = 0.f;
    for (int i = lo + q; i < hi; i += 4) sum += h2[(size_t)i * 64 + c];
    partial[q][c] = sum;
    __syncthreads();
    if (q == 0) {
        float s = partial[0][c] + partial[1][c] + partial[2][c] + partial[3][c];
        int cnt = hi - lo;
        pooled[c] = s / (float)max(cnt, 1);
    }
    __syncthreads();
    if (tid < 64) {
        float acc = fc1_b[tid];
        const float* w = &fc1_w[(size_t)tid * 64];
        #pragma unroll
        for (int k = 0; k < 64; ++k) acc += pooled[k] * w[k];
        hmid[tid] = lrelu(acc, ACT_SLOPE);
    }
    __syncthreads();
    for (int o = tid; o < 768; o += 256) {
        float acc = fc2_b[o];
        const float* w = &fc2_w[(size_t)o * 64];
        #pragma unroll
        for (int k = 0; k < 64; ++k) acc += hmid[k] * w[k];
        out[(size_t)g * 768 + o] = acc;
    }
}

// ---------------- launch ----------------

extern "C" void kernel_launch(void* const* d_in, const int* in_sizes, int n_in,
                              void* d_out, int out_size, void* d_ws, size_t ws_size,
                              hipStream_t stream) {
    const float* x     = (const float*)d_in[0];
    const int*   ei    = (const int*)d_in[1];
    const int*   batch = (const int*)d_in[2];
    const float* w1_l  = (const float*)d_in[3];
    const float* b1_l  = (const float*)d_in[4];
    const float* w1_r  = (const float*)d_in[5];
    const float* b1_r  = (const float*)d_in[6];
    const float* att1  = (const float*)d_in[7];
    const float* bias1 = (const float*)d_in[8];
    const float* w2_l  = (const float*)d_in[9];
    const float* b2_l  = (const float*)d_in[10];
    const float* w2_r  = (const float*)d_in[11];
    const float* b2_r  = (const float*)d_in[12];
    const float* att2  = (const float*)d_in[13];
    const float* bias2 = (const float*)d_in[14];
    const float* fc1_w = (const float*)d_in[15];
    const float* fc1_b = (const float*)d_in[16];
    const float* fc2_w = (const float*)d_in[17];
    const float* fc2_b = (const float*)d_in[18];
    float* out = (float*)d_out;

    const int N = in_sizes[2];
    const int E = in_sizes[1] / 2;
    const int T = E + N;
    const int G = out_size / 768;

    char* ws = (char*)d_ws;
    size_t off = 0;
    auto alloc = [&](size_t bytes) -> void* {
        void* p = ws + off;
        off = (off + bytes + 255) & ~(size_t)255;
        return p;
    };
    int*      deg    = (int*)alloc((size_t)N * 4);
    int*      rowptr = (int*)alloc((size_t)(N + 1) * 4);
    int*      cursor = (int*)alloc((size_t)N * 4);
    int*      bsum   = (int*)alloc(1024);
    int*      boff   = (int*)alloc(1024);
    int*      adj    = (int*)alloc((size_t)T * 4);
    _Float16* h1hi   = (_Float16*)alloc((size_t)N * 128 * 2);
    _Float16* h1lo   = (_Float16*)alloc((size_t)N * 128 * 2);
    _Float16* W1h    = (_Float16*)alloc(32768 * 2);
    _Float16* W1lo   = (_Float16*)alloc(32768 * 2);
    _Float16* W2h    = (_Float16*)alloc(16384 * 2);
    _Float16* W2lo   = (_Float16*)alloc(16384 * 2);
    _Float16* buf1   = (_Float16*)alloc((size_t)N * 256 * 2);
    // lifetime aliasing: buf1 (N*512 B) dead after conv1_fused -> buf2 fp16 [N,128] (N*256 B)
    // in the first half, h2 fp32 [N,64] (N*256 B) in the second half.
    _Float16* buf2 = buf1;
    float*    h2   = (float*)((char*)buf1 + (size_t)N * 256);

    const int nbN  = (N + 255) / 256;
    const int nbT  = (T + 255) / 256;
    const int mfmG = (N / 16 + 7) / 8;          // 16-row tiles, 8 per block
    const int edgG = (N + 3) / 4;

    // ---- CSR build ----
    hipMemsetAsync(deg, 0, (size_t)N * 4, stream);
    k_count<<<nbT, 256, 0, stream>>>(ei, E, N, deg);
    k_scan_block<<<nbN, 256, 0, stream>>>(deg, N, rowptr + 1, bsum);
    k_scan_bsum<<<1, 256, 0, stream>>>(bsum, nbN, boff);
    k_scan_add<<<nbN, 256, 0, stream>>>(rowptr, boff, N);
    hipMemsetAsync(cursor, 0, (size_t)N * 4, stream);
    k_scatter<<<nbT, 256, 0, stream>>>(ei, E, N, rowptr, cursor, adj);

    // ---- weight encode ----
    k_encode_w<<<192, 256, 0, stream>>>(w1_l, w1_r, w2_l, w2_r, W1h, W1lo, W2h, W2lo);

    // ---- conv1 ----
    gemm_mfma<256, true><<<mfmG, 512, 0, stream>>>(x, nullptr, nullptr, N,
                                                   W1h, W1lo, b1_l, b1_r, buf1);
    conv1_fused<<<edgG, 256, 0, stream>>>(buf1, rowptr, adj, att1, bias1, h1hi, h1lo, N);

    // ---- conv2 ----
    gemm_mfma<128, false><<<mfmG, 512, 0, stream>>>(nullptr, h1hi, h1lo, N,
                                                    W2h, W2lo, b2_l, b2_r, buf2);
    conv2_fused<<<edgG, 256, 0, stream>>>(buf2, rowptr, adj, att2, bias2, h2, N);

    // ---- pool + MLP head ----
    pool_mlp<<<G, 256, 0, stream>>>(h2, batch, fc1_w, fc1_b, fc2_w, fc2_b, out, N);
}

// Round 8
// 338.963 us; speedup vs baseline: 2.1753x; 1.0429x over previous
//
#include <hip/hip_runtime.h>

#define ATT_SLOPE 0.2f
#define ACT_SLOPE 0.01f

typedef _Float16 half8  __attribute__((ext_vector_type(8)));
typedef _Float16 half2v __attribute__((ext_vector_type(2)));
typedef float    floatx4 __attribute__((ext_vector_type(4)));

#if defined(__has_builtin)
#if __has_builtin(__builtin_amdgcn_fdot2)
#define HAVE_FDOT2 1
#endif
#endif

__device__ __forceinline__ float lrelu(float v, float s) {
    return fmaxf(v, v * s);
}

__device__ __forceinline__ half2v lrelu2(half2v m) {
    half2v t = m * (_Float16)ATT_SLOPE;
    return __builtin_elementwise_max(m, t);
}

__device__ __forceinline__ float dot2(half2v a, half2v b, float c) {
#ifdef HAVE_FDOT2
    return __builtin_amdgcn_fdot2(a, b, c, false);
#else
    return c + (float)a[0] * (float)b[0] + (float)a[1] * (float)b[1];
#endif
}

// ---------------- CSR build (edges grouped by dst, self loops appended) ----------------

__global__ __launch_bounds__(256) void k_count(const int* __restrict__ ei, int E, int N,
                                               int* __restrict__ deg) {
    int i = blockIdx.x * 256 + threadIdx.x;
    int total = E + N;
    if (i >= total) return;
    int dst = (i < E) ? ei[E + i] : (i - E);
    atomicAdd(&deg[dst], 1);
}

__global__ __launch_bounds__(256) void k_scan_block(const int* __restrict__ deg, int n,
                                                    int* __restrict__ rp1, int* __restrict__ bsum) {
    __shared__ int s[256];
    int tid = threadIdx.x;
    int i = blockIdx.x * 256 + tid;
    s[tid] = (i < n) ? deg[i] : 0;
    __syncthreads();
    for (int off = 1; off < 256; off <<= 1) {
        int t = (tid >= off) ? s[tid - off] : 0;
        __syncthreads();
        s[tid] += t;
        __syncthreads();
    }
    if (i < n) rp1[i] = s[tid];
    if (tid == 255) bsum[blockIdx.x] = s[255];
}

__global__ __launch_bounds__(256) void k_scan_bsum(const int* __restrict__ bsum, int nb,
                                                   int* __restrict__ boff) {
    __shared__ int s[256];
    int tid = threadIdx.x;
    s[tid] = (tid < nb) ? bsum[tid] : 0;
    __syncthreads();
    for (int off = 1; off < 256; off <<= 1) {
        int t = (tid >= off) ? s[tid - off] : 0;
        __syncthreads();
        s[tid] += t;
        __syncthreads();
    }
    if (tid < nb) boff[tid] = (tid > 0) ? s[tid - 1] : 0;
}

__global__ __launch_bounds__(256) void k_scan_add(int* __restrict__ rowptr,
                                                  const int* __restrict__ boff, int n) {
    int i = blockIdx.x * 256 + threadIdx.x;
    if (i < n) rowptr[i + 1] += boff[blockIdx.x];
    if (i == 0) rowptr[0] = 0;
}

__global__ __launch_bounds__(256) void k_scatter(const int* __restrict__ ei, int E, int N,
                                                 const int* __restrict__ rowptr,
                                                 int* __restrict__ cursor,
                                                 int* __restrict__ adj) {
    int i = blockIdx.x * 256 + threadIdx.x;
    int total = E + N;
    if (i >= total) return;
    int src, dst;
    if (i < E) { src = ei[i]; dst = ei[E + i]; } else { src = i - E; dst = i - E; }
    int pos = atomicAdd(&cursor[dst], 1);
    adj[rowptr[dst] + pos] = src;
}

// ---------------- weight hi/lo fp16 split encode (all four matrices, one launch) ------------

__global__ __launch_bounds__(256) void k_encode_w(const float* __restrict__ w1l,
                                                  const float* __restrict__ w1r,
                                                  const float* __restrict__ w2l,
                                                  const float* __restrict__ w2r,
                                                  _Float16* __restrict__ W1h,
                                                  _Float16* __restrict__ W1lo,
                                                  _Float16* __restrict__ W2h,
                                                  _Float16* __restrict__ W2lo) {
    int i = blockIdx.x * 256 + threadIdx.x;   // 0 .. 49151
    if (i >= 49152) return;
    float v;
    _Float16 *ph, *pl;
    int idx;
    if (i < 32768) {
        idx = i;
        v = (i < 16384) ? w1l[i] : w1r[i - 16384];
        ph = W1h; pl = W1lo;
    } else {
        int j = i - 32768;
        idx = j;
        v = (j < 8192) ? w2l[j] : w2r[j - 8192];
        ph = W2h; pl = W2lo;
    }
    _Float16 h = (_Float16)v;
    ph[idx] = h;
    pl[idx] = (_Float16)(v - (float)h);
}

// ---------------- MFMA split-f16 dual linear, LDS-staged W, fp16 out ----------------

template <int COUT, bool IN_F32>
__global__ __launch_bounds__(512) void gemm_mfma(const float* __restrict__ Af,
                                                 const _Float16* __restrict__ Ahi,
                                                 const _Float16* __restrict__ Alo, int n_rows,
                                                 const _Float16* __restrict__ Whi,
                                                 const _Float16* __restrict__ Wlo,
                                                 const float* __restrict__ B0,
                                                 const float* __restrict__ B1,
                                                 _Float16* __restrict__ out) {
    constexpr int NT = COUT / 16;
    constexpr int WS = 40;                      // 32 + 8 pad (16B-aligned)
    __shared__ _Float16 sWh[COUT][WS];
    __shared__ _Float16 sWl[COUT][WS];
    const int tid = threadIdx.x;
    const int lane = tid & 63, wv = tid >> 6;
    const int m = lane & 15, q = lane >> 4;
    const long row0 = ((long)blockIdx.x * 8 + wv) * 16;
    const bool active = row0 < n_rows;          // wave-uniform (n_rows % 16 == 0)
    const long arow = row0 + m;

    floatx4 acc[NT] = {};
    for (int kk = 0; kk < 128; kk += 32) {
        __syncthreads();                        // protect previous phase's reads
        for (int t = tid; t < COUT * 4; t += 512) {
            int c = t >> 2, ch = t & 3;
            *(half8*)&sWh[c][ch * 8] = *(const half8*)&Whi[(size_t)c * 128 + kk + ch * 8];
            *(half8*)&sWl[c][ch * 8] = *(const half8*)&Wlo[(size_t)c * 128 + kk + ch * 8];
        }
        __syncthreads();
        if (active) {
            half8 ah, al;
            if constexpr (IN_F32) {
                float4 a0 = *(const float4*)&Af[(size_t)arow * 128 + kk + q * 8];
                float4 a1 = *(const float4*)&Af[(size_t)arow * 128 + kk + q * 8 + 4];
                float av[8] = {a0.x, a0.y, a0.z, a0.w, a1.x, a1.y, a1.z, a1.w};
                #pragma unroll
                for (int x = 0; x < 8; ++x) {
                    ah[x] = (_Float16)av[x];
                    al[x] = (_Float16)(av[x] - (float)ah[x]);
                }
            } else {
                ah = *(const half8*)&Ahi[(size_t)arow * 128 + kk + q * 8];
                al = *(const half8*)&Alo[(size_t)arow * 128 + kk + q * 8];
            }
            #pragma unroll
            for (int nt = 0; nt < NT; ++nt) {
                half8 bh = *(const half8*)&sWh[nt * 16 + m][q * 8];
                half8 bl = *(const half8*)&sWl[nt * 16 + m][q * 8];
                acc[nt] = __builtin_amdgcn_mfma_f32_16x16x32_f16(ah, bh, acc[nt], 0, 0, 0);
                acc[nt] = __builtin_amdgcn_mfma_f32_16x16x32_f16(al, bh, acc[nt], 0, 0, 0);
                acc[nt] = __builtin_amdgcn_mfma_f32_16x16x32_f16(ah, bl, acc[nt], 0, 0, 0);
            }
        }
    }
    if (active) {
        // C/D layout: col = lane&15, row = (lane>>4)*4 + reg
        #pragma unroll
        for (int nt = 0; nt < NT; ++nt) {
            int col = nt * 16 + m;
            float b = (col < COUT / 2) ? B0[col] : B1[col - COUT / 2];
            #pragma unroll
            for (int r = 0; r < 4; ++r) {
                long grow = row0 + q * 4 + r;
                out[(size_t)grow * COUT + col] = (_Float16)(acc[nt][r] + b);
            }
        }
    }
}

// ---------------- fused GATv2 conv1 edge phase (heads=2, ch=64) ----------------
// Chunk = 16 edges, 4 lanes/edge (each 32 of 128 ch) -> all lanes busy at mean degree 17,
// LDS ~19KB/block -> 8 blocks/CU. Quarter-logits combined via shfl_xor(16).

__global__ __launch_bounds__(256) void conv1_fused(const _Float16* __restrict__ buf,
                                                   const int* __restrict__ rowptr,
                                                   const int* __restrict__ adj,
                                                   const float* __restrict__ att,   // [128]
                                                   const float* __restrict__ bias,  // [128]
                                                   _Float16* __restrict__ h1hi,
                                                   _Float16* __restrict__ h1lo, int n) {
    __shared__ _Float16 sxl[4][16][136];   // 272B row stride, 16B-aligned
    __shared__ _Float16 sxr[4][128];
    __shared__ float    sw[4][2][16];
    __shared__ _Float16 satt[128];
    const int tid = threadIdx.x, lane = tid & 63, wv = tid >> 6;
    if (tid < 128) satt[tid] = (_Float16)att[tid];
    __syncthreads();                        // all threads reach; no block barriers after this
    int node = blockIdx.x * 4 + wv;
    if (node >= n) return;

    const int jlane = lane & 15;           // edge slot within chunk
    const int grp = lane >> 4;             // channel quarter 0..3 (0,1->head0; 2,3->head1)
    const int chq = grp * 32;
    const int head = grp >> 1;
    const int wselg = lane >> 5;           // phase-B head for channels lane*2 (0..127)
    if (lane < 16)
        *(half8*)&sxr[wv][lane * 8] = *(const half8*)&buf[(size_t)node * 256 + 128 + lane * 8];
    asm volatile("s_waitcnt lgkmcnt(0)" ::: "memory");

    const int s = rowptr[node], e = rowptr[node + 1];
    float2 accA = {0.f, 0.f}, accB = {0.f, 0.f};
    float denA = 0.f, denB = 0.f;
    for (int c0 = s; c0 < e; c0 += 16) {
        const int cnt = min(16, e - c0);
        float sacc0 = 0.f, sacc1 = 0.f;
        if (jlane < cnt) {
            int src = adj[c0 + jlane];
            const _Float16* xlp = &buf[(size_t)src * 256 + chq];
            #pragma unroll
            for (int k = 0; k < 4; ++k) {
                half8 l = *(const half8*)&xlp[k * 8];
                half8 r = *(const half8*)&sxr[wv][chq + k * 8];
                half8 a = *(const half8*)&satt[chq + k * 8];
                *(half8*)&sxl[wv][jlane][chq + k * 8] = l;
                float* sp = (k & 1) ? &sacc1 : &sacc0;
                #pragma unroll
                for (int p = 0; p < 4; ++p) {
                    half2v lp = {l[2 * p], l[2 * p + 1]};
                    half2v rp = {r[2 * p], r[2 * p + 1]};
                    half2v ap = {a[2 * p], a[2 * p + 1]};
                    *sp = dot2(lrelu2(lp + rp), ap, *sp);
                }
            }
        }
        float sacc = sacc0 + sacc1;
        float efull = sacc + __shfl_xor(sacc, 16);   // combine the two quarters of this head
        if ((grp & 1) == 0 && jlane < cnt) sw[wv][head][jlane] = __expf(efull);
        asm volatile("s_waitcnt lgkmcnt(0)" ::: "memory");
        // phase B: lane -> channels (2*lane, 2*lane+1); its head's weights; 2-way unroll
        int j = 0;
        for (; j + 1 < cnt; j += 2) {
            float w0 = sw[wv][wselg][j], w1 = sw[wv][wselg][j + 1];
            half2v v0 = *(const half2v*)&sxl[wv][j][lane * 2];
            half2v v1 = *(const half2v*)&sxl[wv][j + 1][lane * 2];
            accA.x += w0 * (float)v0[0]; accA.y += w0 * (float)v0[1]; denA += w0;
            accB.x += w1 * (float)v1[0]; accB.y += w1 * (float)v1[1]; denB += w1;
        }
        if (j < cnt) {
            float w0 = sw[wv][wselg][j];
            half2v v0 = *(const half2v*)&sxl[wv][j][lane * 2];
            accA.x += w0 * (float)v0[0]; accA.y += w0 * (float)v0[1]; denA += w0;
        }
        asm volatile("s_waitcnt lgkmcnt(0)" ::: "memory");  // drain reads before next overwrite
    }
    float inv = 1.f / (denA + denB);
    float2 b = *(const float2*)&bias[lane * 2];
    float ox = lrelu((accA.x + accB.x) * inv + b.x, ACT_SLOPE);
    float oy = lrelu((accA.y + accB.y) * inv + b.y, ACT_SLOPE);
    half2v hv, lv;
    hv[0] = (_Float16)ox; lv[0] = (_Float16)(ox - (float)hv[0]);
    hv[1] = (_Float16)oy; lv[1] = (_Float16)(oy - (float)hv[1]);
    *(half2v*)&h1hi[(size_t)node * 128 + lane * 2] = hv;
    *(half2v*)&h1lo[(size_t)node * 128 + lane * 2] = lv;
}

// ---------------- fused GATv2 conv2 edge phase (heads=1, ch=64) ----------------
// Chunk = 16 edges, 4 lanes/edge (each 16 of 64 ch); logit = xor16 + xor32 combine.

__global__ __launch_bounds__(256) void conv2_fused(const _Float16* __restrict__ buf,
                                                   const int* __restrict__ rowptr,
                                                   const int* __restrict__ adj,
                                                   const float* __restrict__ att,   // [64]
                                                   const float* __restrict__ bias,  // [64]
                                                   float* __restrict__ h2, int n) {
    __shared__ _Float16 sxl[4][16][72];    // 144B row stride, 16B-aligned
    __shared__ _Float16 sxr[4][64];
    __shared__ float    sw[4][16];
    __shared__ _Float16 satt[64];
    const int tid = threadIdx.x, lane = tid & 63, wv = tid >> 6;
    if (tid < 64) satt[tid] = (_Float16)att[tid];
    __syncthreads();
    int node = blockIdx.x * 4 + wv;
    if (node >= n) return;

    const int jlane = lane & 15;
    const int grp = lane >> 4;             // channel quarter 0..3 (16 ch each)
    const int chq = grp * 16;
    if (lane < 8)
        *(half8*)&sxr[wv][lane * 8] = *(const half8*)&buf[(size_t)node * 128 + 64 + lane * 8];
    asm volatile("s_waitcnt lgkmcnt(0)" ::: "memory");

    const int s = rowptr[node], e = rowptr[node + 1];
    float accA = 0.f, accB = 0.f, denA = 0.f, denB = 0.f;
    for (int c0 = s; c0 < e; c0 += 16) {
        const int cnt = min(16, e - c0);
        float sacc = 0.f;
        if (jlane < cnt) {
            int src = adj[c0 + jlane];
            const _Float16* xlp = &buf[(size_t)src * 128 + chq];
            #pragma unroll
            for (int k = 0; k < 2; ++k) {
                half8 l = *(const half8*)&xlp[k * 8];
                half8 r = *(const half8*)&sxr[wv][chq + k * 8];
                half8 a = *(const half8*)&satt[chq + k * 8];
                *(half8*)&sxl[wv][jlane][chq + k * 8] = l;
                #pragma unroll
                for (int p = 0; p < 4; ++p) {
                    half2v lp = {l[2 * p], l[2 * p + 1]};
                    half2v rp = {r[2 * p], r[2 * p + 1]};
                    half2v ap = {a[2 * p], a[2 * p + 1]};
                    sacc = dot2(lrelu2(lp + rp), ap, sacc);
                }
            }
        }
        float s1 = sacc + __shfl_xor(sacc, 16);
        float efull = s1 + __shfl_xor(s1, 32);
        if (grp == 0 && jlane < cnt) sw[wv][jlane] = __expf(efull);
        asm volatile("s_waitcnt lgkmcnt(0)" ::: "memory");
        int j = 0;
        for (; j + 1 < cnt; j += 2) {
            float w0 = sw[wv][j], w1 = sw[wv][j + 1];
            accA += w0 * (float)sxl[wv][j][lane];     denA += w0;
            accB += w1 * (float)sxl[wv][j + 1][lane]; denB += w1;
        }
        if (j < cnt) {
            float w0 = sw[wv][j];
            accA += w0 * (float)sxl[wv][j][lane];
            denA += w0;
        }
        asm volatile("s_waitcnt lgkmcnt(0)" ::: "memory");
    }
    h2[(size_t)node * 64 + lane] = lrelu((accA + accB) / (denA + denB) + bias[lane], ACT_SLOPE);
}

// ---------------- global mean pool (batch sorted) + fc1 + lrelu + fc2 ----------------

__device__ __forceinline__ int lower_bound(const int* a, int n, int v) {
    int lo = 0, hi = n;
    while (lo < hi) { int mid = (lo + hi) >> 1; if (a[mid] < v) lo = mid + 1; else hi = mid; }
    return lo;
}

__global__ __launch_bounds__(256) void pool_mlp(const float* __restrict__ h2,   // [N,64]
                                                const int* __restrict__ batch,  // [N] sorted
                                                const float* __restrict__ fc1_w,
                                                const float* __restrict__ fc1_b,
                                                const float* __restrict__ fc2_w,
                                                const float* __restrict__ fc2_b,
                                                float* __restrict__ out, int n) {
    const int g = blockIdx.x;
    const int tid = threadIdx.x;
    const int c = tid & 63, q = tid >> 6;
    __shared__ float partial[4][64];
    __shared__ float pooled[64];
    __shared__ float hmid[64];

    int lo = lower_bound(batch, n, g);
    int hi = lower_bound(batch, n, g + 1);

    float sum = 0.f;
    for (int i = lo + q; i < hi; i += 4) sum += h2[(size_t)i * 64 + c];
    partial[q][c] = sum;
    __syncthreads();
    if (q == 0) {
        float s = partial[0][c] + partial[1][c] + partial[2][c] + partial[3][c];
        int cnt = hi - lo;
        pooled[c] = s / (float)max(cnt, 1);
    }
    __syncthreads();
    if (tid < 64) {
        float acc = fc1_b[tid];
        const float* w = &fc1_w[(size_t)tid * 64];
        #pragma unroll
        for (int k = 0; k < 64; ++k) acc += pooled[k] * w[k];
        hmid[tid] = lrelu(acc, ACT_SLOPE);
    }
    __syncthreads();
    for (int o = tid; o < 768; o += 256) {
        float acc = fc2_b[o];
        const float* w = &fc2_w[(size_t)o * 64];
        #pragma unroll
        for (int k = 0; k < 64; ++k) acc += hmid[k] * w[k];
        out[(size_t)g * 768 + o] = acc;
    }
}

// ---------------- launch ----------------

extern "C" void kernel_launch(void* const* d_in, const int* in_sizes, int n_in,
                              void* d_out, int out_size, void* d_ws, size_t ws_size,
                              hipStream_t stream) {
    const float* x     = (const float*)d_in[0];
    const int*   ei    = (const int*)d_in[1];
    const int*   batch = (const int*)d_in[2];
    const float* w1_l  = (const float*)d_in[3];
    const float* b1_l  = (const float*)d_in[4];
    const float* w1_r  = (const float*)d_in[5];
    const float* b1_r  = (const float*)d_in[6];
    const float* att1  = (const float*)d_in[7];
    const float* bias1 = (const float*)d_in[8];
    const float* w2_l  = (const float*)d_in[9];
    const float* b2_l  = (const float*)d_in[10];
    const float* w2_r  = (const float*)d_in[11];
    const float* b2_r  = (const float*)d_in[12];
    const float* att2  = (const float*)d_in[13];
    const float* bias2 = (const float*)d_in[14];
    const float* fc1_w = (const float*)d_in[15];
    const float* fc1_b = (const float*)d_in[16];
    const float* fc2_w = (const float*)d_in[17];
    const float* fc2_b = (const float*)d_in[18];
    float* out = (float*)d_out;

    const int N = in_sizes[2];
    const int E = in_sizes[1] / 2;
    const int T = E + N;
    const int G = out_size / 768;

    char* ws = (char*)d_ws;
    size_t off = 0;
    auto alloc = [&](size_t bytes) -> void* {
        void* p = ws + off;
        off = (off + bytes + 255) & ~(size_t)255;
        return p;
    };
    int*      deg    = (int*)alloc((size_t)N * 4);
    int*      rowptr = (int*)alloc((size_t)(N + 1) * 4);
    int*      cursor = (int*)alloc((size_t)N * 4);
    int*      bsum   = (int*)alloc(1024);
    int*      boff   = (int*)alloc(1024);
    int*      adj    = (int*)alloc((size_t)T * 4);
    _Float16* h1hi   = (_Float16*)alloc((size_t)N * 128 * 2);
    _Float16* h1lo   = (_Float16*)alloc((size_t)N * 128 * 2);
    _Float16* W1h    = (_Float16*)alloc(32768 * 2);
    _Float16* W1lo   = (_Float16*)alloc(32768 * 2);
    _Float16* W2h    = (_Float16*)alloc(16384 * 2);
    _Float16* W2lo   = (_Float16*)alloc(16384 * 2);
    _Float16* buf1   = (_Float16*)alloc((size_t)N * 256 * 2);
    // lifetime aliasing: buf1 (N*512 B) dead after conv1_fused -> buf2 fp16 [N,128] (N*256 B)
    // in the first half, h2 fp32 [N,64] (N*256 B) in the second half.
    _Float16* buf2 = buf1;
    float*    h2   = (float*)((char*)buf1 + (size_t)N * 256);

    const int nbN  = (N + 255) / 256;
    const int nbT  = (T + 255) / 256;
    const int mfmG = (N / 16 + 7) / 8;          // 16-row tiles, 8 per block
    const int edgG = (N + 3) / 4;

    // ---- CSR build ----
    hipMemsetAsync(deg, 0, (size_t)N * 4, stream);
    k_count<<<nbT, 256, 0, stream>>>(ei, E, N, deg);
    k_scan_block<<<nbN, 256, 0, stream>>>(deg, N, rowptr + 1, bsum);
    k_scan_bsum<<<1, 256, 0, stream>>>(bsum, nbN, boff);
    k_scan_add<<<nbN, 256, 0, stream>>>(rowptr, boff, N);
    hipMemsetAsync(cursor, 0, (size_t)N * 4, stream);
    k_scatter<<<nbT, 256, 0, stream>>>(ei, E, N, rowptr, cursor, adj);

    // ---- weight encode ----
    k_encode_w<<<192, 256, 0, stream>>>(w1_l, w1_r, w2_l, w2_r, W1h, W1lo, W2h, W2lo);

    // ---- conv1 ----
    gemm_mfma<256, true><<<mfmG, 512, 0, stream>>>(x, nullptr, nullptr, N,
                                                   W1h, W1lo, b1_l, b1_r, buf1);
    conv1_fused<<<edgG, 256, 0, stream>>>(buf1, rowptr, adj, att1, bias1, h1hi, h1lo, N);

    // ---- conv2 ----
    gemm_mfma<128, false><<<mfmG, 512, 0, stream>>>(nullptr, h1hi, h1lo, N,
                                                    W2h, W2lo, b2_l, b2_r, buf2);
    conv2_fused<<<edgG, 256, 0, stream>>>(buf2, rowptr, adj, att2, bias2, h2, N);

    // ---- pool + MLP head ----
    pool_mlp<<<G, 256, 0, stream>>>(h2, batch, fc1_w, fc1_b, fc2_w, fc2_b, out, N);
}

// Round 9
// 298.690 us; speedup vs baseline: 2.4686x; 1.1348x over previous
//
#include <hip/hip_runtime.h>

#define ATT_SLOPE 0.2f
#define ACT_SLOPE 0.01f

typedef _Float16 half8  __attribute__((ext_vector_type(8)));
typedef _Float16 half2v __attribute__((ext_vector_type(2)));
typedef float    floatx4 __attribute__((ext_vector_type(4)));

#if defined(__has_builtin)
#if __has_builtin(__builtin_amdgcn_fdot2)
#define HAVE_FDOT2 1
#endif
#endif

__device__ __forceinline__ float lrelu(float v, float s) {
    return fmaxf(v, v * s);
}

__device__ __forceinline__ half2v lrelu2(half2v m) {
    half2v t = m * (_Float16)ATT_SLOPE;
    return __builtin_elementwise_max(m, t);
}

__device__ __forceinline__ float dot2(half2v a, half2v b, float c) {
#ifdef HAVE_FDOT2
    return __builtin_amdgcn_fdot2(a, b, c, false);
#else
    return c + (float)a[0] * (float)b[0] + (float)a[1] * (float)b[1];
#endif
}

// ---------------- CSR build (edges grouped by dst, self loops appended) ----------------

// count + stable rank within dst (rank write is coalesced)
__global__ __launch_bounds__(256) void k_count_rank(const int* __restrict__ ei, int E, int N,
                                                    int* __restrict__ deg,
                                                    int* __restrict__ rank) {
    int i = blockIdx.x * 256 + threadIdx.x;
    int total = E + N;
    if (i >= total) return;
    int dst = (i < E) ? ei[E + i] : (i - E);
    rank[i] = atomicAdd(&deg[dst], 1);
}

__global__ __launch_bounds__(256) void k_scan_block(const int* __restrict__ deg, int n,
                                                    int* __restrict__ rp1, int* __restrict__ bsum) {
    __shared__ int s[256];
    int tid = threadIdx.x;
    int i = blockIdx.x * 256 + tid;
    s[tid] = (i < n) ? deg[i] : 0;
    __syncthreads();
    for (int off = 1; off < 256; off <<= 1) {
        int t = (tid >= off) ? s[tid - off] : 0;
        __syncthreads();
        s[tid] += t;
        __syncthreads();
    }
    if (i < n) rp1[i] = s[tid];
    if (tid == 255) bsum[blockIdx.x] = s[255];
}

__global__ __launch_bounds__(256) void k_scan_bsum(const int* __restrict__ bsum, int nb,
                                                   int* __restrict__ boff) {
    __shared__ int s[256];
    int tid = threadIdx.x;
    s[tid] = (tid < nb) ? bsum[tid] : 0;
    __syncthreads();
    for (int off = 1; off < 256; off <<= 1) {
        int t = (tid >= off) ? s[tid - off] : 0;
        __syncthreads();
        s[tid] += t;
        __syncthreads();
    }
    if (tid < nb) boff[tid] = (tid > 0) ? s[tid - 1] : 0;
}

__global__ __launch_bounds__(256) void k_scan_add(int* __restrict__ rowptr,
                                                  const int* __restrict__ boff, int n) {
    int i = blockIdx.x * 256 + threadIdx.x;
    if (i < n) rowptr[i + 1] += boff[blockIdx.x];
    if (i == 0) rowptr[0] = 0;
}

// XCD-partitioned owner-writes scatter: block group (blockIdx&7) writes only its 1/8 dst
// range, so each adj cache line is written from (mostly) one XCD L2 -> no cross-XCD
// partial-line write amplification. No atomics (rank precomputed). Grid must be %8==0.
__global__ __launch_bounds__(256) void k_scatter(const int* __restrict__ ei, int E, int N,
                                                 const int* __restrict__ rowptr,
                                                 const int* __restrict__ rank,
                                                 int* __restrict__ adj) {
    const int T = E + N;
    const int part = blockIdx.x & 7;
    const int rng = (N + 7) / 8;
    const int lo = part * rng, hi = min(N, lo + rng);
    const int nb = gridDim.x >> 3;
    for (int base = (int)(blockIdx.x >> 3) * 256; base < T; base += nb * 256) {
        int i = base + threadIdx.x;
        if (i >= T) continue;
        int dst = (i < E) ? ei[E + i] : (i - E);
        if (dst >= lo && dst < hi) {
            int src = (i < E) ? ei[i] : dst;
            adj[rowptr[dst] + rank[i]] = src;
        }
    }
}

// ---------------- weight hi/lo fp16 split encode (all four matrices, one launch) ------------

__global__ __launch_bounds__(256) void k_encode_w(const float* __restrict__ w1l,
                                                  const float* __restrict__ w1r,
                                                  const float* __restrict__ w2l,
                                                  const float* __restrict__ w2r,
                                                  _Float16* __restrict__ W1h,
                                                  _Float16* __restrict__ W1lo,
                                                  _Float16* __restrict__ W2h,
                                                  _Float16* __restrict__ W2lo) {
    int i = blockIdx.x * 256 + threadIdx.x;   // 0 .. 49151
    if (i >= 49152) return;
    float v;
    _Float16 *ph, *pl;
    int idx;
    if (i < 32768) {
        idx = i;
        v = (i < 16384) ? w1l[i] : w1r[i - 16384];
        ph = W1h; pl = W1lo;
    } else {
        int j = i - 32768;
        idx = j;
        v = (j < 8192) ? w2l[j] : w2r[j - 8192];
        ph = W2h; pl = W2lo;
    }
    _Float16 h = (_Float16)v;
    ph[idx] = h;
    pl[idx] = (_Float16)(v - (float)h);
}

// ---------------- MFMA split-f16 dual linear, LDS-staged W, fp16 out ----------------

template <int COUT, bool IN_F32>
__global__ __launch_bounds__(512) void gemm_mfma(const float* __restrict__ Af,
                                                 const _Float16* __restrict__ Ahi,
                                                 const _Float16* __restrict__ Alo, int n_rows,
                                                 const _Float16* __restrict__ Whi,
                                                 const _Float16* __restrict__ Wlo,
                                                 const float* __restrict__ B0,
                                                 const float* __restrict__ B1,
                                                 _Float16* __restrict__ out) {
    constexpr int NT = COUT / 16;
    constexpr int WS = 40;                      // 32 + 8 pad (16B-aligned)
    __shared__ _Float16 sWh[COUT][WS];
    __shared__ _Float16 sWl[COUT][WS];
    const int tid = threadIdx.x;
    const int lane = tid & 63, wv = tid >> 6;
    const int m = lane & 15, q = lane >> 4;
    const long row0 = ((long)blockIdx.x * 8 + wv) * 16;
    const bool active = row0 < n_rows;          // wave-uniform (n_rows % 16 == 0)
    const long arow = row0 + m;

    floatx4 acc[NT] = {};
    for (int kk = 0; kk < 128; kk += 32) {
        __syncthreads();                        // protect previous phase's reads
        for (int t = tid; t < COUT * 4; t += 512) {
            int c = t >> 2, ch = t & 3;
            *(half8*)&sWh[c][ch * 8] = *(const half8*)&Whi[(size_t)c * 128 + kk + ch * 8];
            *(half8*)&sWl[c][ch * 8] = *(const half8*)&Wlo[(size_t)c * 128 + kk + ch * 8];
        }
        __syncthreads();
        if (active) {
            half8 ah, al;
            if constexpr (IN_F32) {
                float4 a0 = *(const float4*)&Af[(size_t)arow * 128 + kk + q * 8];
                float4 a1 = *(const float4*)&Af[(size_t)arow * 128 + kk + q * 8 + 4];
                float av[8] = {a0.x, a0.y, a0.z, a0.w, a1.x, a1.y, a1.z, a1.w};
                #pragma unroll
                for (int x = 0; x < 8; ++x) {
                    ah[x] = (_Float16)av[x];
                    al[x] = (_Float16)(av[x] - (float)ah[x]);
                }
            } else {
                ah = *(const half8*)&Ahi[(size_t)arow * 128 + kk + q * 8];
                al = *(const half8*)&Alo[(size_t)arow * 128 + kk + q * 8];
            }
            #pragma unroll
            for (int nt = 0; nt < NT; ++nt) {
                half8 bh = *(const half8*)&sWh[nt * 16 + m][q * 8];
                half8 bl = *(const half8*)&sWl[nt * 16 + m][q * 8];
                acc[nt] = __builtin_amdgcn_mfma_f32_16x16x32_f16(ah, bh, acc[nt], 0, 0, 0);
                acc[nt] = __builtin_amdgcn_mfma_f32_16x16x32_f16(al, bh, acc[nt], 0, 0, 0);
                acc[nt] = __builtin_amdgcn_mfma_f32_16x16x32_f16(ah, bl, acc[nt], 0, 0, 0);
            }
        }
    }
    if (active) {
        // C/D layout: col = lane&15, row = (lane>>4)*4 + reg
        #pragma unroll
        for (int nt = 0; nt < NT; ++nt) {
            int col = nt * 16 + m;
            float b = (col < COUT / 2) ? B0[col] : B1[col - COUT / 2];
            #pragma unroll
            for (int r = 0; r < 4; ++r) {
                long grow = row0 + q * 4 + r;
                out[(size_t)grow * COUT + col] = (_Float16)(acc[nt][r] + b);
            }
        }
    }
}

// ---------------- fused GATv2 conv1 edge phase (heads=2, ch=64) ----------------
// Chunk = 16 edges, 4 lanes/edge (each 32 of 128 ch); quarter-logits via shfl_xor(16).

__global__ __launch_bounds__(256) void conv1_fused(const _Float16* __restrict__ buf,
                                                   const int* __restrict__ rowptr,
                                                   const int* __restrict__ adj,
                                                   const float* __restrict__ att,   // [128]
                                                   const float* __restrict__ bias,  // [128]
                                                   _Float16* __restrict__ h1hi,
                                                   _Float16* __restrict__ h1lo, int n) {
    __shared__ _Float16 sxl[4][16][136];   // 272B row stride, 16B-aligned
    __shared__ _Float16 sxr[4][128];
    __shared__ float    sw[4][2][16];
    __shared__ _Float16 satt[128];
    const int tid = threadIdx.x, lane = tid & 63, wv = tid >> 6;
    if (tid < 128) satt[tid] = (_Float16)att[tid];
    __syncthreads();                        // all threads reach; no block barriers after this
    int node = blockIdx.x * 4 + wv;
    if (node >= n) return;

    const int jlane = lane & 15;           // edge slot within chunk
    const int grp = lane >> 4;             // channel quarter 0..3 (0,1->head0; 2,3->head1)
    const int chq = grp * 32;
    const int head = grp >> 1;
    const int wselg = lane >> 5;           // phase-B head for channels lane*2 (0..127)
    if (lane < 16)
        *(half8*)&sxr[wv][lane * 8] = *(const half8*)&buf[(size_t)node * 256 + 128 + lane * 8];
    asm volatile("s_waitcnt lgkmcnt(0)" ::: "memory");

    const int s = rowptr[node], e = rowptr[node + 1];
    float2 accA = {0.f, 0.f}, accB = {0.f, 0.f};
    float denA = 0.f, denB = 0.f;
    for (int c0 = s; c0 < e; c0 += 16) {
        const int cnt = min(16, e - c0);
        float sacc0 = 0.f, sacc1 = 0.f;
        if (jlane < cnt) {
            int src = adj[c0 + jlane];
            const _Float16* xlp = &buf[(size_t)src * 256 + chq];
            #pragma unroll
            for (int k = 0; k < 4; ++k) {
                half8 l = *(const half8*)&xlp[k * 8];
                half8 r = *(const half8*)&sxr[wv][chq + k * 8];
                half8 a = *(const half8*)&satt[chq + k * 8];
                *(half8*)&sxl[wv][jlane][chq + k * 8] = l;
                float* sp = (k & 1) ? &sacc1 : &sacc0;
                #pragma unroll
                for (int p = 0; p < 4; ++p) {
                    half2v lp = {l[2 * p], l[2 * p + 1]};
                    half2v rp = {r[2 * p], r[2 * p + 1]};
                    half2v ap = {a[2 * p], a[2 * p + 1]};
                    *sp = dot2(lrelu2(lp + rp), ap, *sp);
                }
            }
        }
        float sacc = sacc0 + sacc1;
        float efull = sacc + __shfl_xor(sacc, 16);   // combine the two quarters of this head
        if ((grp & 1) == 0 && jlane < cnt) sw[wv][head][jlane] = __expf(efull);
        asm volatile("s_waitcnt lgkmcnt(0)" ::: "memory");
        // phase B: lane -> channels (2*lane, 2*lane+1); its head's weights; 2-way unroll
        int j = 0;
        for (; j + 1 < cnt; j += 2) {
            float w0 = sw[wv][wselg][j], w1 = sw[wv][wselg][j + 1];
            half2v v0 = *(const half2v*)&sxl[wv][j][lane * 2];
            half2v v1 = *(const half2v*)&sxl[wv][j + 1][lane * 2];
            accA.x += w0 * (float)v0[0]; accA.y += w0 * (float)v0[1]; denA += w0;
            accB.x += w1 * (float)v1[0]; accB.y += w1 * (float)v1[1]; denB += w1;
        }
        if (j < cnt) {
            float w0 = sw[wv][wselg][j];
            half2v v0 = *(const half2v*)&sxl[wv][j][lane * 2];
            accA.x += w0 * (float)v0[0]; accA.y += w0 * (float)v0[1]; denA += w0;
        }
        asm volatile("s_waitcnt lgkmcnt(0)" ::: "memory");  // drain reads before next overwrite
    }
    float inv = 1.f / (denA + denB);
    float2 b = *(const float2*)&bias[lane * 2];
    float ox = lrelu((accA.x + accB.x) * inv + b.x, ACT_SLOPE);
    float oy = lrelu((accA.y + accB.y) * inv + b.y, ACT_SLOPE);
    half2v hv, lv;
    hv[0] = (_Float16)ox; lv[0] = (_Float16)(ox - (float)hv[0]);
    hv[1] = (_Float16)oy; lv[1] = (_Float16)(oy - (float)hv[1]);
    *(half2v*)&h1hi[(size_t)node * 128 + lane * 2] = hv;
    *(half2v*)&h1lo[(size_t)node * 128 + lane * 2] = lv;
}

// ---------------- fused GATv2 conv2 edge phase (heads=1, ch=64) ----------------

__global__ __launch_bounds__(256) void conv2_fused(const _Float16* __restrict__ buf,
                                                   const int* __restrict__ rowptr,
                                                   const int* __restrict__ adj,
                                                   const float* __restrict__ att,   // [64]
                                                   const float* __restrict__ bias,  // [64]
                                                   float* __restrict__ h2, int n) {
    __shared__ _Float16 sxl[4][16][72];    // 144B row stride, 16B-aligned
    __shared__ _Float16 sxr[4][64];
    __shared__ float    sw[4][16];
    __shared__ _Float16 satt[64];
    const int tid = threadIdx.x, lane = tid & 63, wv = tid >> 6;
    if (tid < 64) satt[tid] = (_Float16)att[tid];
    __syncthreads();
    int node = blockIdx.x * 4 + wv;
    if (node >= n) return;

    const int jlane = lane & 15;
    const int grp = lane >> 4;             // channel quarter 0..3 (16 ch each)
    const int chq = grp * 16;
    if (lane < 8)
        *(half8*)&sxr[wv][lane * 8] = *(const half8*)&buf[(size_t)node * 128 + 64 + lane * 8];
    asm volatile("s_waitcnt lgkmcnt(0)" ::: "memory");

    const int s = rowptr[node], e = rowptr[node + 1];
    float accA = 0.f, accB = 0.f, denA = 0.f, denB = 0.f;
    for (int c0 = s; c0 < e; c0 += 16) {
        const int cnt = min(16, e - c0);
        float sacc = 0.f;
        if (jlane < cnt) {
            int src = adj[c0 + jlane];
            const _Float16* xlp = &buf[(size_t)src * 128 + chq];
            #pragma unroll
            for (int k = 0; k < 2; ++k) {
                half8 l = *(const half8*)&xlp[k * 8];
                half8 r = *(const half8*)&sxr[wv][chq + k * 8];
                half8 a = *(const half8*)&satt[chq + k * 8];
                *(half8*)&sxl[wv][jlane][chq + k * 8] = l;
                #pragma unroll
                for (int p = 0; p < 4; ++p) {
                    half2v lp = {l[2 * p], l[2 * p + 1]};
                    half2v rp = {r[2 * p], r[2 * p + 1]};
                    half2v ap = {a[2 * p], a[2 * p + 1]};
                    sacc = dot2(lrelu2(lp + rp), ap, sacc);
                }
            }
        }
        float s1 = sacc + __shfl_xor(sacc, 16);
        float efull = s1 + __shfl_xor(s1, 32);
        if (grp == 0 && jlane < cnt) sw[wv][jlane] = __expf(efull);
        asm volatile("s_waitcnt lgkmcnt(0)" ::: "memory");
        int j = 0;
        for (; j + 1 < cnt; j += 2) {
            float w0 = sw[wv][j], w1 = sw[wv][j + 1];
            accA += w0 * (float)sxl[wv][j][lane];     denA += w0;
            accB += w1 * (float)sxl[wv][j + 1][lane]; denB += w1;
        }
        if (j < cnt) {
            float w0 = sw[wv][j];
            accA += w0 * (float)sxl[wv][j][lane];
            denA += w0;
        }
        asm volatile("s_waitcnt lgkmcnt(0)" ::: "memory");
    }
    h2[(size_t)node * 64 + lane] = lrelu((accA + accB) / (denA + denB) + bias[lane], ACT_SLOPE);
}

// ---------------- global mean pool (batch sorted) + fc1 + lrelu + fc2 ----------------

__device__ __forceinline__ int lower_bound(const int* a, int n, int v) {
    int lo = 0, hi = n;
    while (lo < hi) { int mid = (lo + hi) >> 1; if (a[mid] < v) lo = mid + 1; else hi = mid; }
    return lo;
}

__global__ __launch_bounds__(256) void pool_mlp(const float* __restrict__ h2,   // [N,64]
                                                const int* __restrict__ batch,  // [N] sorted
                                                const float* __restrict__ fc1_w,
                                                const float* __restrict__ fc1_b,
                                                const float* __restrict__ fc2_w,
                                                const float* __restrict__ fc2_b,
                                                float* __restrict__ out, int n) {
    const int g = blockIdx.x;
    const int tid = threadIdx.x;
    const int c = tid & 63, q = tid >> 6;
    __shared__ float partial[4][64];
    __shared__ float pooled[64];
    __shared__ float hmid[64];

    int lo = lower_bound(batch, n, g);
    int hi = lower_bound(batch, n, g + 1);

    float sum = 0.f;
    for (int i = lo + q; i < hi; i += 4) sum += h2[(size_t)i * 64 + c];
    partial[q][c] = sum;
    __syncthreads();
    if (q == 0) {
        float s = partial[0][c] + partial[1][c] + partial[2][c] + partial[3][c];
        int cnt = hi - lo;
        pooled[c] = s / (float)max(cnt, 1);
    }
    __syncthreads();
    if (tid < 64) {
        float acc = fc1_b[tid];
        const float* w = &fc1_w[(size_t)tid * 64];
        #pragma unroll
        for (int k = 0; k < 64; ++k) acc += pooled[k] * w[k];
        hmid[tid] = lrelu(acc, ACT_SLOPE);
    }
    __syncthreads();
    for (int o = tid; o < 768; o += 256) {
        float acc = fc2_b[o];
        const float* w = &fc2_w[(size_t)o * 64];
        #pragma unroll
        for (int k = 0; k < 64; ++k) acc += hmid[k] * w[k];
        out[(size_t)g * 768 + o] = acc;
    }
}

// ---------------- launch ----------------

extern "C" void kernel_launch(void* const* d_in, const int* in_sizes, int n_in,
                              void* d_out, int out_size, void* d_ws, size_t ws_size,
                              hipStream_t stream) {
    const float* x     = (const float*)d_in[0];
    const int*   ei    = (const int*)d_in[1];
    const int*   batch = (const int*)d_in[2];
    const float* w1_l  = (const float*)d_in[3];
    const float* b1_l  = (const float*)d_in[4];
    const float* w1_r  = (const float*)d_in[5];
    const float* b1_r  = (const float*)d_in[6];
    const float* att1  = (const float*)d_in[7];
    const float* bias1 = (const float*)d_in[8];
    const float* w2_l  = (const float*)d_in[9];
    const float* b2_l  = (const float*)d_in[10];
    const float* w2_r  = (const float*)d_in[11];
    const float* b2_r  = (const float*)d_in[12];
    const float* att2  = (const float*)d_in[13];
    const float* bias2 = (const float*)d_in[14];
    const float* fc1_w = (const float*)d_in[15];
    const float* fc1_b = (const float*)d_in[16];
    const float* fc2_w = (const float*)d_in[17];
    const float* fc2_b = (const float*)d_in[18];
    float* out = (float*)d_out;

    const int N = in_sizes[2];
    const int E = in_sizes[1] / 2;
    const int T = E + N;
    const int G = out_size / 768;

    char* ws = (char*)d_ws;
    size_t off = 0;
    auto alloc = [&](size_t bytes) -> void* {
        void* p = ws + off;
        off = (off + bytes + 255) & ~(size_t)255;
        return p;
    };
    int*      deg    = (int*)alloc((size_t)N * 4);
    int*      rowptr = (int*)alloc((size_t)(N + 1) * 4);
    int*      rank   = (int*)alloc((size_t)T * 4);
    int*      bsum   = (int*)alloc(1024);
    int*      boff   = (int*)alloc(1024);
    int*      adj    = (int*)alloc((size_t)T * 4);
    _Float16* h1hi   = (_Float16*)alloc((size_t)N * 128 * 2);
    _Float16* h1lo   = (_Float16*)alloc((size_t)N * 128 * 2);
    _Float16* W1h    = (_Float16*)alloc(32768 * 2);
    _Float16* W1lo   = (_Float16*)alloc(32768 * 2);
    _Float16* W2h    = (_Float16*)alloc(16384 * 2);
    _Float16* W2lo   = (_Float16*)alloc(16384 * 2);
    _Float16* buf1   = (_Float16*)alloc((size_t)N * 256 * 2);
    // lifetime aliasing: buf1 (N*512 B) dead after conv1_fused -> buf2 fp16 [N,128] (N*256 B)
    // in the first half, h2 fp32 [N,64] (N*256 B) in the second half.
    _Float16* buf2 = buf1;
    float*    h2   = (float*)((char*)buf1 + (size_t)N * 256);

    const int nbN  = (N + 255) / 256;
    const int nbT  = (T + 255) / 256;
    const int mfmG = (N / 16 + 7) / 8;          // 16-row tiles, 8 per block
    const int edgG = (N + 3) / 4;

    // ---- CSR build ----
    hipMemsetAsync(deg, 0, (size_t)N * 4, stream);
    k_count_rank<<<nbT, 256, 0, stream>>>(ei, E, N, deg, rank);
    k_scan_block<<<nbN, 256, 0, stream>>>(deg, N, rowptr + 1, bsum);
    k_scan_bsum<<<1, 256, 0, stream>>>(bsum, nbN, boff);
    k_scan_add<<<nbN, 256, 0, stream>>>(rowptr, boff, N);
    k_scatter<<<2048, 256, 0, stream>>>(ei, E, N, rowptr, rank, adj);

    // ---- weight encode ----
    k_encode_w<<<192, 256, 0, stream>>>(w1_l, w1_r, w2_l, w2_r, W1h, W1lo, W2h, W2lo);

    // ---- conv1 ----
    gemm_mfma<256, true><<<mfmG, 512, 0, stream>>>(x, nullptr, nullptr, N,
                                                   W1h, W1lo, b1_l, b1_r, buf1);
    conv1_fused<<<edgG, 256, 0, stream>>>(buf1, rowptr, adj, att1, bias1, h1hi, h1lo, N);

    // ---- conv2 ----
    gemm_mfma<128, false><<<mfmG, 512, 0, stream>>>(nullptr, h1hi, h1lo, N,
                                                    W2h, W2lo, b2_l, b2_r, buf2);
    conv2_fused<<<edgG, 256, 0, stream>>>(buf2, rowptr, adj, att2, bias2, h2, N);

    // ---- pool + MLP head ----
    pool_mlp<<<G, 256, 0, stream>>>(h2, batch, fc1_w, fc1_b, fc2_w, fc2_b, out, N);
}